// Round 1
// baseline (463.951 us; speedup 1.0000x reference)
//
#include <hip/hip_runtime.h>

#define LQ 1024
#define CS 768
#define CZ 64
#define NH 12
#define HD 64

using f4 = float4;

static __device__ __forceinline__ unsigned short f2bf(float f) {
  unsigned int u = __float_as_uint(f);
  u += 0x7fffu + ((u >> 16) & 1u);
  return (unsigned short)(u >> 16);
}
static __device__ __forceinline__ float bf2f(unsigned short b) {
  return __uint_as_float(((unsigned int)b) << 16);
}

// ---------------- LayerNorm of single -> s ----------------
__global__ __launch_bounds__(256) void ln_single_k(
    const float* __restrict__ x, const float* __restrict__ g,
    const float* __restrict__ b, float* __restrict__ out) {
  const int row = blockIdx.x;
  const int t = threadIdx.x;
  const float* xr = x + (size_t)row * CS;
  float v0 = xr[t], v1 = xr[t + 256], v2 = xr[t + 512];
  float s1 = v0 + v1 + v2;
  float s2 = v0 * v0 + v1 * v1 + v2 * v2;
#pragma unroll
  for (int m = 1; m < 64; m <<= 1) {
    s1 += __shfl_xor(s1, m);
    s2 += __shfl_xor(s2, m);
  }
  __shared__ float r1[4], r2[4];
  const int wid = t >> 6;
  if ((t & 63) == 0) { r1[wid] = s1; r2[wid] = s2; }
  __syncthreads();
  s1 = r1[0] + r1[1] + r1[2] + r1[3];
  s2 = r2[0] + r2[1] + r2[2] + r2[3];
  const float mu = s1 * (1.f / CS);
  const float var = s2 * (1.f / CS) - mu * mu;
  const float rs = rsqrtf(var + 1e-5f);
  out[(size_t)row * CS + t]       = (v0 - mu) * rs * g[t]       + b[t];
  out[(size_t)row * CS + t + 256] = (v1 - mu) * rs * g[t + 256] + b[t + 256];
  out[(size_t)row * CS + t + 512] = (v2 - mu) * rs * g[t + 512] + b[t + 512];
}

// ---------------- pair LN + projection to per-head bias (bf16) ----------------
// grid (1024, 16), block 256. Block handles row i, 64 consecutive j.
// 4 lanes per (i,j) pair, 16 channels each.
__global__ __launch_bounds__(256) void pair_bias_k(
    const float* __restrict__ pair, const float* __restrict__ zg,
    const float* __restrict__ zb, const float* __restrict__ Wb,
    unsigned short* __restrict__ bias) {
  const int i = blockIdx.x;
  const int j0 = blockIdx.y * 64;
  const int t = threadIdx.x;
  const int p = t >> 2;    // pair within tile (0..63)
  const int qtr = t & 3;   // channel quarter

  __shared__ float WbL[CZ][13];
  __shared__ float zgL[CZ], zbL[CZ];
  __shared__ float tile[NH][64];
  if (t < CZ) { zgL[t] = zg[t]; zbL[t] = zb[t]; }
  for (int idx = t; idx < CZ * NH; idx += 256) WbL[idx / NH][idx % NH] = Wb[idx];
  __syncthreads();

  const float* src = pair + ((size_t)i * LQ + (j0 + p)) * CZ + qtr * 16;
  float x[16];
  *(f4*)&x[0]  = ((const f4*)src)[0];
  *(f4*)&x[4]  = ((const f4*)src)[1];
  *(f4*)&x[8]  = ((const f4*)src)[2];
  *(f4*)&x[12] = ((const f4*)src)[3];
  float s1 = 0.f, s2 = 0.f;
#pragma unroll
  for (int c = 0; c < 16; ++c) { s1 += x[c]; s2 += x[c] * x[c]; }
  s1 += __shfl_xor(s1, 1); s2 += __shfl_xor(s2, 1);
  s1 += __shfl_xor(s1, 2); s2 += __shfl_xor(s2, 2);
  const float mu = s1 * (1.f / CZ);
  const float var = s2 * (1.f / CZ) - mu * mu;
  const float rs = rsqrtf(var + 1e-5f);

  float pb[NH];
#pragma unroll
  for (int h = 0; h < NH; ++h) pb[h] = 0.f;
  const int c0 = qtr * 16;
#pragma unroll
  for (int c = 0; c < 16; ++c) {
    const float zn = (x[c] - mu) * rs * zgL[c0 + c] + zbL[c0 + c];
#pragma unroll
    for (int h = 0; h < NH; ++h) pb[h] += zn * WbL[c0 + c][h];
  }
#pragma unroll
  for (int h = 0; h < NH; ++h) {
    pb[h] += __shfl_xor(pb[h], 1);
    pb[h] += __shfl_xor(pb[h], 2);
  }
  if (qtr == 0) {
#pragma unroll
    for (int h = 0; h < NH; ++h) tile[h][p] = pb[h];
  }
  __syncthreads();
  for (int idx = t; idx < NH * 64; idx += 256) {
    const int h = idx >> 6, jj = idx & 63;
    bias[(size_t)h * LQ * LQ + (size_t)i * LQ + j0 + jj] = f2bf(tile[h][jj]);
  }
}

// ---------------- fp32 tiled GEMM body: C[128x128] tile of A[M,K]@B[K,N] ----------------
__device__ __forceinline__ void gemm_body(const float* __restrict__ A,
                                          const float* __restrict__ B,
                                          int m0, int n0,
                                          float (*As)[132], float (*Bs)[132],
                                          float acc[8][8]) {
  const int t = threadIdx.x;
  const int ty = t >> 4, tx = t & 15;
  for (int kt = 0; kt < CS; kt += 8) {
    __syncthreads();
    {
      const f4 av = *(const f4*)(A + (size_t)(m0 + (t >> 1)) * CS + kt + (t & 1) * 4);
      const int kk = (t & 1) * 4, m = t >> 1;
      As[kk + 0][m] = av.x; As[kk + 1][m] = av.y;
      As[kk + 2][m] = av.z; As[kk + 3][m] = av.w;
      const f4 bv = *(const f4*)(B + (size_t)(kt + (t >> 5)) * CS + n0 + (t & 31) * 4);
      *(f4*)&Bs[t >> 5][(t & 31) * 4] = bv;
    }
    __syncthreads();
#pragma unroll
    for (int kk = 0; kk < 8; ++kk) {
      const f4 a0 = *(const f4*)&As[kk][ty * 8];
      const f4 a1 = *(const f4*)&As[kk][ty * 8 + 4];
      const f4 b0 = *(const f4*)&Bs[kk][tx * 4];
      const f4 b1 = *(const f4*)&Bs[kk][tx * 4 + 64];
      const float aa[8] = {a0.x, a0.y, a0.z, a0.w, a1.x, a1.y, a1.z, a1.w};
      const float bb[8] = {b0.x, b0.y, b0.z, b0.w, b1.x, b1.y, b1.z, b1.w};
#pragma unroll
      for (int i = 0; i < 8; ++i)
#pragma unroll
        for (int j = 0; j < 8; ++j) acc[i][j] += aa[i] * bb[j];
    }
  }
}

// ---------------- q,k,v,gate_pre GEMMs (grid.z selects weight) ----------------
__global__ __launch_bounds__(256) void gemm_qkvg_k(
    const float* __restrict__ s,
    const float* __restrict__ Wq, const float* __restrict__ Wk,
    const float* __restrict__ Wv, const float* __restrict__ Wg,
    const float* __restrict__ bg,
    float* __restrict__ q, float* __restrict__ kk2, float* __restrict__ v,
    float* __restrict__ g) {
  __shared__ float As[8][132], Bs[8][132];
  const float* B; float* C; bool hasb = false;
  switch (blockIdx.z) {
    case 0: B = Wq; C = q; break;
    case 1: B = Wk; C = kk2; break;
    case 2: B = Wv; C = v; break;
    default: B = Wg; C = g; hasb = true; break;
  }
  float acc[8][8] = {};
  const int m0 = blockIdx.y * 128, n0 = blockIdx.x * 128;
  gemm_body(s, B, m0, n0, As, Bs, acc);
  const int t = threadIdx.x, ty = t >> 4, tx = t & 15;
#pragma unroll
  for (int i = 0; i < 8; ++i) {
    const int m = m0 + ty * 8 + i;
#pragma unroll
    for (int hh = 0; hh < 2; ++hh) {
      const int n = n0 + hh * 64 + tx * 4;
      f4 c;
      c.x = acc[i][hh * 4 + 0]; c.y = acc[i][hh * 4 + 1];
      c.z = acc[i][hh * 4 + 2]; c.w = acc[i][hh * 4 + 3];
      if (hasb) { c.x += bg[n]; c.y += bg[n + 1]; c.z += bg[n + 2]; c.w += bg[n + 3]; }
      *(f4*)&C[(size_t)m * CS + n] = c;
    }
  }
}

// ---------------- flash attention with precomputed bf16 bias ----------------
// grid (16, 12): 64-row i-tile x head. block 256 = 16x16 threads, 4x4 microtile.
__global__ __launch_bounds__(256) void attn_k(
    const float* __restrict__ q, const float* __restrict__ k,
    const float* __restrict__ v, const unsigned short* __restrict__ bias,
    float* __restrict__ attno) {
  __shared__ float QT[64][68];
  __shared__ float KT[64][68];
  __shared__ float Vs[64][68];
  __shared__ unsigned short Ps[64][72];
  const int i0 = blockIdx.x * 64;
  const int h = blockIdx.y;
  const int t = threadIdx.x;
  const int ty = t >> 4, tx = t & 15;
  const int r = t >> 2, dq = (t & 3) * 16;

  {  // load Q tile transposed: QT[d][row]
    const float* src = q + (size_t)(i0 + r) * CS + h * HD + dq;
    float tmp[16];
    *(f4*)&tmp[0]  = ((const f4*)src)[0];
    *(f4*)&tmp[4]  = ((const f4*)src)[1];
    *(f4*)&tmp[8]  = ((const f4*)src)[2];
    *(f4*)&tmp[12] = ((const f4*)src)[3];
#pragma unroll
    for (int u = 0; u < 16; ++u) QT[dq + u][r] = tmp[u];
  }

  float acc[4][4] = {};
  float mrow[4] = {-1e30f, -1e30f, -1e30f, -1e30f};
  float lrow[4] = {0.f, 0.f, 0.f, 0.f};

  for (int jt = 0; jt < 16; ++jt) {
    const int j0 = jt * 64;
    __syncthreads();  // previous iter LDS use done (and QT visible on iter 0)
    {
      const float* ks = k + (size_t)(j0 + r) * CS + h * HD + dq;
      float tmp[16];
      *(f4*)&tmp[0]  = ((const f4*)ks)[0];
      *(f4*)&tmp[4]  = ((const f4*)ks)[1];
      *(f4*)&tmp[8]  = ((const f4*)ks)[2];
      *(f4*)&tmp[12] = ((const f4*)ks)[3];
#pragma unroll
      for (int u = 0; u < 16; ++u) KT[dq + u][r] = tmp[u];
      const float* vs = v + (size_t)(j0 + r) * CS + h * HD + dq;
      *(f4*)&Vs[r][dq]      = ((const f4*)vs)[0];
      *(f4*)&Vs[r][dq + 4]  = ((const f4*)vs)[1];
      *(f4*)&Vs[r][dq + 8]  = ((const f4*)vs)[2];
      *(f4*)&Vs[r][dq + 12] = ((const f4*)vs)[3];
    }
    __syncthreads();

    // S = (Q K^T)/8 + bias for this 64x64 tile; thread owns 4x4
    float sv[4][4] = {};
#pragma unroll 4
    for (int d = 0; d < 64; ++d) {
      const f4 qa = *(const f4*)&QT[d][ty * 4];
      const f4 kb = *(const f4*)&KT[d][tx * 4];
      const float aa[4] = {qa.x, qa.y, qa.z, qa.w};
      const float bb[4] = {kb.x, kb.y, kb.z, kb.w};
#pragma unroll
      for (int i2 = 0; i2 < 4; ++i2)
#pragma unroll
        for (int j2 = 0; j2 < 4; ++j2) sv[i2][j2] += aa[i2] * bb[j2];
    }

#pragma unroll
    for (int i2 = 0; i2 < 4; ++i2) {
      const ushort4 bw = *(const ushort4*)(bias + (size_t)h * LQ * LQ +
                                           (size_t)(i0 + ty * 4 + i2) * LQ + j0 + tx * 4);
      sv[i2][0] = sv[i2][0] * 0.125f + bf2f(bw.x);
      sv[i2][1] = sv[i2][1] * 0.125f + bf2f(bw.y);
      sv[i2][2] = sv[i2][2] * 0.125f + bf2f(bw.z);
      sv[i2][3] = sv[i2][3] * 0.125f + bf2f(bw.w);
      float mt = fmaxf(fmaxf(sv[i2][0], sv[i2][1]), fmaxf(sv[i2][2], sv[i2][3]));
#pragma unroll
      for (int mm = 1; mm < 16; mm <<= 1) mt = fmaxf(mt, __shfl_xor(mt, mm));
      const float mnew = fmaxf(mrow[i2], mt);
      const float scale = __expf(mrow[i2] - mnew);
      float ps = 0.f;
      unsigned short pb[4];
#pragma unroll
      for (int j2 = 0; j2 < 4; ++j2) {
        const float p = __expf(sv[i2][j2] - mnew);
        ps += p;
        pb[j2] = f2bf(p);
        acc[i2][j2] *= scale;
      }
#pragma unroll
      for (int mm = 1; mm < 16; mm <<= 1) ps += __shfl_xor(ps, mm);
      lrow[i2] = lrow[i2] * scale + ps;
      mrow[i2] = mnew;
      ushort4 pw; pw.x = pb[0]; pw.y = pb[1]; pw.z = pb[2]; pw.w = pb[3];
      *(ushort4*)&Ps[ty * 4 + i2][tx * 4] = pw;
    }
    __syncthreads();  // Ps complete before PV

    // acc += P @ V  (thread owns rows ty*4.., d-cols tx*4..)
#pragma unroll 4
    for (int j = 0; j < 64; ++j) {
      const f4 vv = *(const f4*)&Vs[j][tx * 4];
#pragma unroll
      for (int i2 = 0; i2 < 4; ++i2) {
        const float p = bf2f(Ps[ty * 4 + i2][j]);
        acc[i2][0] += p * vv.x;
        acc[i2][1] += p * vv.y;
        acc[i2][2] += p * vv.z;
        acc[i2][3] += p * vv.w;
      }
    }
  }

#pragma unroll
  for (int i2 = 0; i2 < 4; ++i2) {
    const float inv = 1.f / lrow[i2];
    f4 o;
    o.x = acc[i2][0] * inv; o.y = acc[i2][1] * inv;
    o.z = acc[i2][2] * inv; o.w = acc[i2][3] * inv;
    *(f4*)&attno[(size_t)(i0 + ty * 4 + i2) * CS + h * HD + tx * 4] = o;
  }
}

// ---------------- final GEMM + gated residual epilogue ----------------
__global__ __launch_bounds__(256) void gemm_final_k(
    const float* __restrict__ A, const float* __restrict__ W,
    const float* __restrict__ bout, const float* __restrict__ single,
    const float* __restrict__ gpre, float* __restrict__ out) {
  __shared__ float As[8][132], Bs[8][132];
  float acc[8][8] = {};
  const int m0 = blockIdx.y * 128, n0 = blockIdx.x * 128;
  gemm_body(A, W, m0, n0, As, Bs, acc);
  const int t = threadIdx.x, ty = t >> 4, tx = t & 15;
#pragma unroll
  for (int i = 0; i < 8; ++i) {
    const int m = m0 + ty * 8 + i;
#pragma unroll
    for (int hh = 0; hh < 2; ++hh) {
      const int n = n0 + hh * 64 + tx * 4;
      const f4 sg = *(const f4*)&single[(size_t)m * CS + n];
      const f4 gp = *(const f4*)&gpre[(size_t)m * CS + n];
      const float ss[4] = {sg.x, sg.y, sg.z, sg.w};
      const float gg[4] = {gp.x, gp.y, gp.z, gp.w};
      float rr[4];
#pragma unroll
      for (int u = 0; u < 4; ++u) {
        const float c = acc[i][hh * 4 + u] + bout[n + u];
        const float gate = 1.f / (1.f + __expf(-gg[u]));
        rr[u] = ss[u] + gate * c;
      }
      *(f4*)&out[(size_t)m * CS + n] = *(const f4*)rr;
    }
  }
}

extern "C" void kernel_launch(void* const* d_in, const int* in_sizes, int n_in,
                              void* d_out, int out_size, void* d_ws, size_t ws_size,
                              hipStream_t stream) {
  const float* single = (const float*)d_in[0];
  const float* pair   = (const float*)d_in[1];
  const float* ln_s_g = (const float*)d_in[2];
  const float* ln_s_b = (const float*)d_in[3];
  const float* ln_z_g = (const float*)d_in[4];
  const float* ln_z_b = (const float*)d_in[5];
  const float* Wq     = (const float*)d_in[6];
  const float* Wk     = (const float*)d_in[7];
  const float* Wv     = (const float*)d_in[8];
  const float* Wb     = (const float*)d_in[9];
  const float* Wout   = (const float*)d_in[10];
  const float* bout   = (const float*)d_in[11];
  const float* Wgate  = (const float*)d_in[12];
  const float* bgate  = (const float*)d_in[13];
  float* out = (float*)d_out;

  float* ws = (float*)d_ws;
  float* s     = ws;
  float* qb    = s    + (size_t)LQ * CS;
  float* kb    = qb   + (size_t)LQ * CS;
  float* vb    = kb   + (size_t)LQ * CS;
  float* gpre  = vb   + (size_t)LQ * CS;
  float* attno = gpre + (size_t)LQ * CS;
  unsigned short* bias = (unsigned short*)(attno + (size_t)LQ * CS);

  hipLaunchKernelGGL(ln_single_k, dim3(LQ), dim3(256), 0, stream,
                     single, ln_s_g, ln_s_b, s);
  hipLaunchKernelGGL(pair_bias_k, dim3(LQ, 16), dim3(256), 0, stream,
                     pair, ln_z_g, ln_z_b, Wb, bias);
  hipLaunchKernelGGL(gemm_qkvg_k, dim3(6, 8, 4), dim3(256), 0, stream,
                     s, Wq, Wk, Wv, Wgate, bgate, qb, kb, vb, gpre);
  hipLaunchKernelGGL(attn_k, dim3(16, NH), dim3(256), 0, stream,
                     qb, kb, vb, bias, attno);
  hipLaunchKernelGGL(gemm_final_k, dim3(6, 8), dim3(256), 0, stream,
                     attno, Wout, bout, single, gpre, out);
}

// Round 2
// 201.938 us; speedup vs baseline: 2.2975x; 2.2975x over previous
//
#include <hip/hip_runtime.h>

#define LQ 1024
#define CS 768
#define CZ 64
#define NH 12
#define HD 64

typedef float4 f4;
using bf16x8 = __attribute__((ext_vector_type(8))) short;
using f32x4  = __attribute__((ext_vector_type(4))) float;

static __device__ __forceinline__ unsigned short f2bf(float f) {
  unsigned int u = __float_as_uint(f);
  u += 0x7fffu + ((u >> 16) & 1u);
  return (unsigned short)(u >> 16);
}
static __device__ __forceinline__ float bf2f(unsigned short b) {
  return __uint_as_float(((unsigned int)b) << 16);
}

// ---------------- LayerNorm of single -> s (bf16) ----------------
__global__ __launch_bounds__(256) void ln_single_k(
    const float* __restrict__ x, const float* __restrict__ g,
    const float* __restrict__ b, unsigned short* __restrict__ out) {
  const int row = blockIdx.x;
  const int t = threadIdx.x;
  const float* xr = x + (size_t)row * CS;
  float v0 = xr[t], v1 = xr[t + 256], v2 = xr[t + 512];
  float s1 = v0 + v1 + v2;
  float s2 = v0 * v0 + v1 * v1 + v2 * v2;
#pragma unroll
  for (int m = 1; m < 64; m <<= 1) {
    s1 += __shfl_xor(s1, m);
    s2 += __shfl_xor(s2, m);
  }
  __shared__ float r1[4], r2[4];
  const int wid = t >> 6;
  if ((t & 63) == 0) { r1[wid] = s1; r2[wid] = s2; }
  __syncthreads();
  s1 = r1[0] + r1[1] + r1[2] + r1[3];
  s2 = r2[0] + r2[1] + r2[2] + r2[3];
  const float mu = s1 * (1.f / CS);
  const float var = s2 * (1.f / CS) - mu * mu;
  const float rs = rsqrtf(var + 1e-5f);
  out[(size_t)row * CS + t]       = f2bf((v0 - mu) * rs * g[t]       + b[t]);
  out[(size_t)row * CS + t + 256] = f2bf((v1 - mu) * rs * g[t + 256] + b[t + 256]);
  out[(size_t)row * CS + t + 512] = f2bf((v2 - mu) * rs * g[t + 512] + b[t + 512]);
}

// ---------------- weight convert + transpose: wt[z][n][k] = bf16(W[k][n]) ----------------
__global__ __launch_bounds__(256) void wconv_k(
    const float* __restrict__ Wq, const float* __restrict__ Wk,
    const float* __restrict__ Wv, const float* __restrict__ Wg,
    const float* __restrict__ Wo, unsigned short* __restrict__ wt) {
  const float* W;
  switch (blockIdx.z) {
    case 0: W = Wq; break;
    case 1: W = Wk; break;
    case 2: W = Wv; break;
    case 3: W = Wg; break;
    default: W = Wo; break;
  }
  unsigned short* out = wt + (size_t)blockIdx.z * CS * CS;
  const int n0 = blockIdx.x * 64, k0 = blockIdx.y * 64;
  const int t = threadIdx.x;
  __shared__ float T[64][68];
  {
    const int r = t >> 4, c = (t & 15) * 4;
#pragma unroll
    for (int u = 0; u < 4; ++u) {
      const f4 v = *(const f4*)&W[(size_t)(k0 + r + u * 16) * CS + n0 + c];
      *(f4*)&T[r + u * 16][c] = v;
    }
  }
  __syncthreads();
  {
    const int rn = t >> 2, ck = (t & 3) * 16;
    __align__(16) unsigned short tmp[16];
#pragma unroll
    for (int u = 0; u < 16; ++u) tmp[u] = f2bf(T[ck + u][rn]);
    unsigned short* dst = &out[(size_t)(n0 + rn) * CS + k0 + ck];
    *(uint4*)dst = ((const uint4*)tmp)[0];
    *(uint4*)(dst + 8) = ((const uint4*)tmp)[1];
  }
}

// ---------------- pair LN + projection to per-head bias (bf16) ----------------
__global__ __launch_bounds__(256) void pair_bias_k(
    const float* __restrict__ pair, const float* __restrict__ zg,
    const float* __restrict__ zb, const float* __restrict__ Wb,
    unsigned short* __restrict__ bias) {
  const int i = blockIdx.x;
  const int j0 = blockIdx.y * 64;
  const int t = threadIdx.x;
  const int p = t >> 2;
  const int qtr = t & 3;

  __shared__ float WbL[CZ][13];
  __shared__ float zgL[CZ], zbL[CZ];
  __shared__ float tile[NH][64];
  if (t < CZ) { zgL[t] = zg[t]; zbL[t] = zb[t]; }
  for (int idx = t; idx < CZ * NH; idx += 256) WbL[idx / NH][idx % NH] = Wb[idx];
  __syncthreads();

  const float* src = pair + ((size_t)i * LQ + (j0 + p)) * CZ + qtr * 16;
  float x[16];
  *(f4*)&x[0]  = ((const f4*)src)[0];
  *(f4*)&x[4]  = ((const f4*)src)[1];
  *(f4*)&x[8]  = ((const f4*)src)[2];
  *(f4*)&x[12] = ((const f4*)src)[3];
  float s1 = 0.f, s2 = 0.f;
#pragma unroll
  for (int c = 0; c < 16; ++c) { s1 += x[c]; s2 += x[c] * x[c]; }
  s1 += __shfl_xor(s1, 1); s2 += __shfl_xor(s2, 1);
  s1 += __shfl_xor(s1, 2); s2 += __shfl_xor(s2, 2);
  const float mu = s1 * (1.f / CZ);
  const float var = s2 * (1.f / CZ) - mu * mu;
  const float rs = rsqrtf(var + 1e-5f);

  float pb[NH];
#pragma unroll
  for (int h = 0; h < NH; ++h) pb[h] = 0.f;
  const int c0 = qtr * 16;
#pragma unroll
  for (int c = 0; c < 16; ++c) {
    const float zn = (x[c] - mu) * rs * zgL[c0 + c] + zbL[c0 + c];
#pragma unroll
    for (int h = 0; h < NH; ++h) pb[h] += zn * WbL[c0 + c][h];
  }
#pragma unroll
  for (int h = 0; h < NH; ++h) {
    pb[h] += __shfl_xor(pb[h], 1);
    pb[h] += __shfl_xor(pb[h], 2);
  }
  if (qtr == 0) {
#pragma unroll
    for (int h = 0; h < NH; ++h) tile[h][p] = pb[h];
  }
  __syncthreads();
  for (int idx = t; idx < NH * 64; idx += 256) {
    const int h = idx >> 6, jj = idx & 63;
    bias[(size_t)h * LQ * LQ + (size_t)i * LQ + j0 + jj] = f2bf(tile[h][jj]);
  }
}

// ---------------- fused QKVG GEMM (bf16 MFMA) ----------------
// grid (24, 8): x = N-tile over [q|k|v|gate] (each 6 tiles of 128), y = M-tile.
__global__ __launch_bounds__(256) void gemm_qkvg_k(
    const unsigned short* __restrict__ s, const unsigned short* __restrict__ wt,
    const float* __restrict__ bg,
    unsigned short* __restrict__ qb, unsigned short* __restrict__ kb,
    unsigned short* __restrict__ vt, float* __restrict__ gpre) {
  __shared__ __align__(16) unsigned short As[128][88];
  __shared__ __align__(16) unsigned short Bs[128][88];
  const int t = threadIdx.x;
  const int wave = t >> 6, lane = t & 63, g = lane >> 4, c = lane & 15;
  const int wm = wave >> 1, wn = wave & 1;
  const int m0 = blockIdx.y * 128;
  const int wid = blockIdx.x / 6;
  const int nl0 = (blockIdx.x % 6) * 128;
  const unsigned short* B = wt + (size_t)wid * CS * CS;

  f32x4 acc[4][4];
#pragma unroll
  for (int i = 0; i < 4; ++i)
#pragma unroll
    for (int j = 0; j < 4; ++j) acc[i][j] = (f32x4){0.f, 0.f, 0.f, 0.f};

  const int sr = t >> 1, sh = (t & 1) * 32;
  for (int kt = 0; kt < CS; kt += 64) {
    __syncthreads();
#pragma unroll
    for (int u = 0; u < 4; ++u) {
      const uint4 av = *(const uint4*)&s[(size_t)(m0 + sr) * CS + kt + sh + u * 8];
      *(uint4*)&As[sr][sh + u * 8] = av;
      const uint4 bv = *(const uint4*)&B[(size_t)(nl0 + sr) * CS + kt + sh + u * 8];
      *(uint4*)&Bs[sr][sh + u * 8] = bv;
    }
    __syncthreads();
#pragma unroll
    for (int kk = 0; kk < 64; kk += 32) {
      bf16x8 af[4], bfr[4];
#pragma unroll
      for (int i = 0; i < 4; ++i)
        af[i] = *(const bf16x8*)&As[wm * 64 + i * 16 + c][kk + g * 8];
#pragma unroll
      for (int j = 0; j < 4; ++j)
        bfr[j] = *(const bf16x8*)&Bs[wn * 64 + j * 16 + c][kk + g * 8];
#pragma unroll
      for (int i = 0; i < 4; ++i)
#pragma unroll
        for (int j = 0; j < 4; ++j)
          acc[i][j] = __builtin_amdgcn_mfma_f32_16x16x32_bf16(af[i], bfr[j], acc[i][j], 0, 0, 0);
    }
  }

#pragma unroll
  for (int i = 0; i < 4; ++i) {
#pragma unroll
    for (int j = 0; j < 4; ++j) {
      const int mb = m0 + wm * 64 + i * 16 + g * 4;
      const int nn = nl0 + wn * 64 + j * 16 + c;
      const f32x4 a = acc[i][j];
      if (wid == 0) {
#pragma unroll
        for (int r = 0; r < 4; ++r)
          qb[(size_t)(mb + r) * CS + nn] = f2bf(a[r] * 0.125f);  // pre-scale q by 1/sqrt(HD)
      } else if (wid == 1) {
#pragma unroll
        for (int r = 0; r < 4; ++r)
          kb[(size_t)(mb + r) * CS + nn] = f2bf(a[r]);
      } else if (wid == 2) {
        ushort4 pk;
        pk.x = f2bf(a[0]); pk.y = f2bf(a[1]); pk.z = f2bf(a[2]); pk.w = f2bf(a[3]);
        *(ushort4*)&vt[(size_t)nn * LQ + mb] = pk;  // transposed: vt[n][m]
      } else {
        const float bb = bg[nn];
#pragma unroll
        for (int r = 0; r < 4; ++r)
          gpre[(size_t)(mb + r) * CS + nn] = a[r] + bb;
      }
    }
  }
}

// ---------------- MFMA flash attention with bias as C-init ----------------
// grid (16, 12): 64-row i-tile x head. 4 waves, wave w owns rows w*16..w*16+15.
__global__ __launch_bounds__(256) void attn_k(
    const unsigned short* __restrict__ q, const unsigned short* __restrict__ k,
    const unsigned short* __restrict__ vt, const unsigned short* __restrict__ bias,
    unsigned short* __restrict__ attno) {
  __shared__ __align__(16) unsigned short Qs[64][88];
  __shared__ __align__(16) unsigned short Ks[64][88];
  __shared__ __align__(16) unsigned short Vts[64][88];
  __shared__ __align__(16) unsigned short Bb[64][72];
  __shared__ __align__(16) unsigned short Ps[4][16][88];
  const int i0 = blockIdx.x * 64;
  const int h = blockIdx.y;
  const int t = threadIdx.x;
  const int w = t >> 6, lane = t & 63, g = lane >> 4, c = lane & 15;
  const int sr = t >> 2, sc = (t & 3) * 16;

  // stage Q tile [64 rows][64 d]
#pragma unroll
  for (int u = 0; u < 2; ++u) {
    const uint4 v = *(const uint4*)&q[(size_t)(i0 + sr) * CS + h * HD + sc + u * 8];
    *(uint4*)&Qs[sr][sc + u * 8] = v;
  }
  __syncthreads();
  bf16x8 aq[2];
  aq[0] = *(const bf16x8*)&Qs[w * 16 + c][g * 8];
  aq[1] = *(const bf16x8*)&Qs[w * 16 + c][32 + g * 8];

  f32x4 acc_o[4];
#pragma unroll
  for (int nb = 0; nb < 4; ++nb) acc_o[nb] = (f32x4){0.f, 0.f, 0.f, 0.f};
  float m_run[4] = {-1e30f, -1e30f, -1e30f, -1e30f};
  float l_run[4] = {0.f, 0.f, 0.f, 0.f};

  for (int jt = 0; jt < 16; ++jt) {
    const int j0 = jt * 64;
    __syncthreads();  // previous iteration's K/Vt/Bb reads complete
#pragma unroll
    for (int u = 0; u < 2; ++u) {
      const uint4 kv = *(const uint4*)&k[(size_t)(j0 + sr) * CS + h * HD + sc + u * 8];
      *(uint4*)&Ks[sr][sc + u * 8] = kv;
      const uint4 vv = *(const uint4*)&vt[(size_t)(h * HD + sr) * LQ + j0 + sc + u * 8];
      *(uint4*)&Vts[sr][sc + u * 8] = vv;
      const uint4 bv = *(const uint4*)&bias[(size_t)h * LQ * LQ + (size_t)(i0 + sr) * LQ + j0 + sc + u * 8];
      *(uint2*)&Bb[sr][sc + u * 8]     = make_uint2(bv.x, bv.y);
      *(uint2*)&Bb[sr][sc + u * 8 + 4] = make_uint2(bv.z, bv.w);
    }
    __syncthreads();

    // S = bias + (Q/8) K^T   (bias enters as MFMA C operand)
    f32x4 sa[4];
#pragma unroll
    for (int nb = 0; nb < 4; ++nb) {
      f32x4 ci;
#pragma unroll
      for (int r = 0; r < 4; ++r) ci[r] = bf2f(Bb[w * 16 + g * 4 + r][nb * 16 + c]);
      const bf16x8 b0 = *(const bf16x8*)&Ks[nb * 16 + c][g * 8];
      const bf16x8 b1 = *(const bf16x8*)&Ks[nb * 16 + c][32 + g * 8];
      ci = __builtin_amdgcn_mfma_f32_16x16x32_bf16(aq[0], b0, ci, 0, 0, 0);
      ci = __builtin_amdgcn_mfma_f32_16x16x32_bf16(aq[1], b1, ci, 0, 0, 0);
      sa[nb] = ci;
    }

    // online softmax over this 64-j tile (D-layout: row g*4+r, col c)
    float mt[4];
#pragma unroll
    for (int r = 0; r < 4; ++r) {
      float v = fmaxf(fmaxf(sa[0][r], sa[1][r]), fmaxf(sa[2][r], sa[3][r]));
      v = fmaxf(v, __shfl_xor(v, 1));
      v = fmaxf(v, __shfl_xor(v, 2));
      v = fmaxf(v, __shfl_xor(v, 4));
      v = fmaxf(v, __shfl_xor(v, 8));
      mt[r] = v;
    }
    float scale[4], ps[4];
#pragma unroll
    for (int r = 0; r < 4; ++r) {
      const float mn = fmaxf(m_run[r], mt[r]);
      scale[r] = __expf(m_run[r] - mn);
      m_run[r] = mn;
      ps[r] = 0.f;
    }
#pragma unroll
    for (int nb = 0; nb < 4; ++nb) {
#pragma unroll
      for (int r = 0; r < 4; ++r) {
        const float p = __expf(sa[nb][r] - m_run[r]);
        ps[r] += p;
        Ps[w][g * 4 + r][nb * 16 + c] = f2bf(p);
      }
    }
#pragma unroll
    for (int r = 0; r < 4; ++r) {
      float v = ps[r];
      v += __shfl_xor(v, 1);
      v += __shfl_xor(v, 2);
      v += __shfl_xor(v, 4);
      v += __shfl_xor(v, 8);
      l_run[r] = l_run[r] * scale[r] + v;
#pragma unroll
      for (int nb = 0; nb < 4; ++nb) acc_o[nb][r] *= scale[r];
    }

    // O += P @ V (P is per-wave private in LDS; same-wave in-order, no barrier)
#pragma unroll
    for (int kb = 0; kb < 2; ++kb) {
      const bf16x8 pa = *(const bf16x8*)&Ps[w][c][kb * 32 + g * 8];
#pragma unroll
      for (int nb = 0; nb < 4; ++nb) {
        const bf16x8 bv = *(const bf16x8*)&Vts[nb * 16 + c][kb * 32 + g * 8];
        acc_o[nb] = __builtin_amdgcn_mfma_f32_16x16x32_bf16(pa, bv, acc_o[nb], 0, 0, 0);
      }
    }
  }

#pragma unroll
  for (int nb = 0; nb < 4; ++nb) {
#pragma unroll
    for (int r = 0; r < 4; ++r) {
      const float o = acc_o[nb][r] / l_run[r];
      attno[(size_t)(i0 + w * 16 + g * 4 + r) * CS + h * HD + nb * 16 + c] = f2bf(o);
    }
  }
}

// ---------------- final GEMM (bf16 MFMA) + gated residual epilogue ----------------
__global__ __launch_bounds__(256) void gemm_final_k(
    const unsigned short* __restrict__ A, const unsigned short* __restrict__ wt,
    const float* __restrict__ bout, const float* __restrict__ single,
    const float* __restrict__ gpre, float* __restrict__ out) {
  __shared__ __align__(16) unsigned short As[128][88];
  __shared__ __align__(16) unsigned short Bs[128][88];
  const int t = threadIdx.x;
  const int wave = t >> 6, lane = t & 63, g = lane >> 4, c = lane & 15;
  const int wm = wave >> 1, wn = wave & 1;
  const int m0 = blockIdx.y * 128;
  const int nl0 = blockIdx.x * 128;
  const unsigned short* B = wt + (size_t)4 * CS * CS;  // Wout^T

  f32x4 acc[4][4];
#pragma unroll
  for (int i = 0; i < 4; ++i)
#pragma unroll
    for (int j = 0; j < 4; ++j) acc[i][j] = (f32x4){0.f, 0.f, 0.f, 0.f};

  const int sr = t >> 1, sh = (t & 1) * 32;
  for (int kt = 0; kt < CS; kt += 64) {
    __syncthreads();
#pragma unroll
    for (int u = 0; u < 4; ++u) {
      const uint4 av = *(const uint4*)&A[(size_t)(m0 + sr) * CS + kt + sh + u * 8];
      *(uint4*)&As[sr][sh + u * 8] = av;
      const uint4 bv = *(const uint4*)&B[(size_t)(nl0 + sr) * CS + kt + sh + u * 8];
      *(uint4*)&Bs[sr][sh + u * 8] = bv;
    }
    __syncthreads();
#pragma unroll
    for (int kk = 0; kk < 64; kk += 32) {
      bf16x8 af[4], bfr[4];
#pragma unroll
      for (int i = 0; i < 4; ++i)
        af[i] = *(const bf16x8*)&As[wm * 64 + i * 16 + c][kk + g * 8];
#pragma unroll
      for (int j = 0; j < 4; ++j)
        bfr[j] = *(const bf16x8*)&Bs[wn * 64 + j * 16 + c][kk + g * 8];
#pragma unroll
      for (int i = 0; i < 4; ++i)
#pragma unroll
        for (int j = 0; j < 4; ++j)
          acc[i][j] = __builtin_amdgcn_mfma_f32_16x16x32_bf16(af[i], bfr[j], acc[i][j], 0, 0, 0);
    }
  }

#pragma unroll
  for (int i = 0; i < 4; ++i) {
#pragma unroll
    for (int j = 0; j < 4; ++j) {
      const int mb = m0 + wm * 64 + i * 16 + g * 4;
      const int nn = nl0 + wn * 64 + j * 16 + c;
      const float bb = bout[nn];
      const f32x4 a = acc[i][j];
#pragma unroll
      for (int r = 0; r < 4; ++r) {
        const size_t idx = (size_t)(mb + r) * CS + nn;
        const float gate = 1.f / (1.f + __expf(-gpre[idx]));
        out[idx] = single[idx] + gate * (a[r] + bb);
      }
    }
  }
}

extern "C" void kernel_launch(void* const* d_in, const int* in_sizes, int n_in,
                              void* d_out, int out_size, void* d_ws, size_t ws_size,
                              hipStream_t stream) {
  const float* single = (const float*)d_in[0];
  const float* pair   = (const float*)d_in[1];
  const float* ln_s_g = (const float*)d_in[2];
  const float* ln_s_b = (const float*)d_in[3];
  const float* ln_z_g = (const float*)d_in[4];
  const float* ln_z_b = (const float*)d_in[5];
  const float* Wq     = (const float*)d_in[6];
  const float* Wk     = (const float*)d_in[7];
  const float* Wv     = (const float*)d_in[8];
  const float* Wb     = (const float*)d_in[9];
  const float* Wout   = (const float*)d_in[10];
  const float* bout   = (const float*)d_in[11];
  const float* Wgate  = (const float*)d_in[12];
  const float* bgate  = (const float*)d_in[13];
  float* out = (float*)d_out;

  unsigned short* s_bf    = (unsigned short*)d_ws;
  unsigned short* wt      = s_bf + (size_t)LQ * CS;
  unsigned short* q_bf    = wt + (size_t)5 * CS * CS;
  unsigned short* k_bf    = q_bf + (size_t)LQ * CS;
  unsigned short* vt_bf   = k_bf + (size_t)LQ * CS;
  unsigned short* attno   = vt_bf + (size_t)CS * LQ;
  unsigned short* bias    = attno + (size_t)LQ * CS;
  float* gpre = (float*)(bias + (size_t)NH * LQ * LQ);

  hipLaunchKernelGGL(ln_single_k, dim3(LQ), dim3(256), 0, stream,
                     single, ln_s_g, ln_s_b, s_bf);
  hipLaunchKernelGGL(wconv_k, dim3(12, 12, 5), dim3(256), 0, stream,
                     Wq, Wk, Wv, Wgate, Wout, wt);
  hipLaunchKernelGGL(pair_bias_k, dim3(LQ, 16), dim3(256), 0, stream,
                     pair, ln_z_g, ln_z_b, Wb, bias);
  hipLaunchKernelGGL(gemm_qkvg_k, dim3(24, 8), dim3(256), 0, stream,
                     s_bf, wt, bgate, q_bf, k_bf, vt_bf, gpre);
  hipLaunchKernelGGL(attn_k, dim3(16, NH), dim3(256), 0, stream,
                     q_bf, k_bf, vt_bf, bias, attno);
  hipLaunchKernelGGL(gemm_final_k, dim3(6, 8), dim3(256), 0, stream,
                     attno, wt, bout, single, gpre, out);
}

// Round 3
// 166.375 us; speedup vs baseline: 2.7886x; 1.2138x over previous
//
#include <hip/hip_runtime.h>

#define LQ 1024
#define CS 768
#define CZ 64
#define NH 12
#define HD 64

typedef float4 f4;
using bf16x8 = __attribute__((ext_vector_type(8))) short;
using f32x4  = __attribute__((ext_vector_type(4))) float;

static __device__ __forceinline__ unsigned short f2bf(float f) {
  unsigned int u = __float_as_uint(f);
  u += 0x7fffu + ((u >> 16) & 1u);
  return (unsigned short)(u >> 16);
}
static __device__ __forceinline__ float bf2f(unsigned short b) {
  return __uint_as_float(((unsigned int)b) << 16);
}

// ============ kernel 1: ln_single + weight convert/transpose (fused) ============
__global__ __launch_bounds__(256) void ln_wconv_k(
    const float* __restrict__ x, const float* __restrict__ g,
    const float* __restrict__ b, unsigned short* __restrict__ s_out,
    const float* __restrict__ Wq, const float* __restrict__ Wk,
    const float* __restrict__ Wv, const float* __restrict__ Wg,
    const float* __restrict__ Wo, unsigned short* __restrict__ wt) {
  const int bid = blockIdx.x;
  const int t = threadIdx.x;
  if (bid < LQ) {
    const int row = bid;
    const float* xr = x + (size_t)row * CS;
    float v0 = xr[t], v1 = xr[t + 256], v2 = xr[t + 512];
    float s1 = v0 + v1 + v2;
    float s2 = v0 * v0 + v1 * v1 + v2 * v2;
#pragma unroll
    for (int m = 1; m < 64; m <<= 1) {
      s1 += __shfl_xor(s1, m);
      s2 += __shfl_xor(s2, m);
    }
    __shared__ float r1[4], r2[4];
    const int wid = t >> 6;
    if ((t & 63) == 0) { r1[wid] = s1; r2[wid] = s2; }
    __syncthreads();
    s1 = r1[0] + r1[1] + r1[2] + r1[3];
    s2 = r2[0] + r2[1] + r2[2] + r2[3];
    const float mu = s1 * (1.f / CS);
    const float var = s2 * (1.f / CS) - mu * mu;
    const float rs = rsqrtf(var + 1e-5f);
    s_out[(size_t)row * CS + t]       = f2bf((v0 - mu) * rs * g[t]       + b[t]);
    s_out[(size_t)row * CS + t + 256] = f2bf((v1 - mu) * rs * g[t + 256] + b[t + 256]);
    s_out[(size_t)row * CS + t + 512] = f2bf((v2 - mu) * rs * g[t + 512] + b[t + 512]);
  } else {
    int r = bid - LQ;                    // 0..719
    const int bz = r / 144; r %= 144;
    const int n0 = (r % 12) * 64, k0 = (r / 12) * 64;
    const float* W;
    switch (bz) {
      case 0: W = Wq; break;
      case 1: W = Wk; break;
      case 2: W = Wv; break;
      case 3: W = Wg; break;
      default: W = Wo; break;
    }
    unsigned short* o = wt + (size_t)bz * CS * CS;
    __shared__ float T[64][68];
    {
      const int rr = t >> 4, c = (t & 15) * 4;
#pragma unroll
      for (int u = 0; u < 4; ++u) {
        const f4 v = *(const f4*)&W[(size_t)(k0 + rr + u * 16) * CS + n0 + c];
        *(f4*)&T[rr + u * 16][c] = v;
      }
    }
    __syncthreads();
    {
      const int rn = t >> 2, ck = (t & 3) * 16;
      __align__(16) unsigned short tmp[16];
#pragma unroll
      for (int u = 0; u < 16; ++u) tmp[u] = f2bf(T[ck + u][rn]);
      unsigned short* dst = &o[(size_t)(n0 + rn) * CS + k0 + ck];
      *(uint4*)dst = ((const uint4*)tmp)[0];
      *(uint4*)(dst + 8) = ((const uint4*)tmp)[1];
    }
  }
}

// ============ kernel 2: fused QKVG GEMM (192 blocks) || pair-bias MFMA (4096 blocks) ============
// bias written in attention-fragment layout:
//   flat = (((h*64+gi)*16 + jtg)*4 + nb)*256 + lane*4 + r
// where gi=i>>4, (i&15)=(lane>>4)*4+r, jtg=j>>6, nb=(j>>4)&3, (j&15)=lane&15.
__global__ __launch_bounds__(256) void qkvg_pair_k(
    const unsigned short* __restrict__ s, const unsigned short* __restrict__ wt,
    const float* __restrict__ bg,
    unsigned short* __restrict__ qb, unsigned short* __restrict__ kb,
    unsigned short* __restrict__ vt, float* __restrict__ gpre,
    const float* __restrict__ pair, const float* __restrict__ zg,
    const float* __restrict__ zb, const float* __restrict__ Wb,
    unsigned short* __restrict__ biasF) {
  __shared__ __align__(16) unsigned short sm[2 * 128 * 88];  // 45 KB, shared by both paths
  __shared__ float zgL[CZ], zbL[CZ];
  const int bid = blockIdx.x;
  const int t = threadIdx.x;

  if (bid < 192) {
    // ---- QKVG GEMM path ----
    unsigned short (*As)[88] = (unsigned short (*)[88])sm;
    unsigned short (*Bs)[88] = (unsigned short (*)[88])(sm + 128 * 88);
    const int wave = t >> 6, lane = t & 63, g = lane >> 4, c = lane & 15;
    const int wm = wave >> 1, wn = wave & 1;
    const int bx = bid % 24, by = bid / 24;
    const int m0 = by * 128;
    const int wid = bx / 6;
    const int nl0 = (bx % 6) * 128;
    const unsigned short* B = wt + (size_t)wid * CS * CS;

    f32x4 acc[4][4];
#pragma unroll
    for (int i = 0; i < 4; ++i)
#pragma unroll
      for (int j = 0; j < 4; ++j) acc[i][j] = (f32x4){0.f, 0.f, 0.f, 0.f};

    const int sr = t >> 1, sh = (t & 1) * 32;
    for (int kt = 0; kt < CS; kt += 64) {
      __syncthreads();
#pragma unroll
      for (int u = 0; u < 4; ++u) {
        *(uint4*)&As[sr][sh + u * 8] = *(const uint4*)&s[(size_t)(m0 + sr) * CS + kt + sh + u * 8];
        *(uint4*)&Bs[sr][sh + u * 8] = *(const uint4*)&B[(size_t)(nl0 + sr) * CS + kt + sh + u * 8];
      }
      __syncthreads();
#pragma unroll
      for (int kk = 0; kk < 64; kk += 32) {
        bf16x8 af[4], bfr[4];
#pragma unroll
        for (int i = 0; i < 4; ++i) af[i] = *(const bf16x8*)&As[wm * 64 + i * 16 + c][kk + g * 8];
#pragma unroll
        for (int j = 0; j < 4; ++j) bfr[j] = *(const bf16x8*)&Bs[wn * 64 + j * 16 + c][kk + g * 8];
#pragma unroll
        for (int i = 0; i < 4; ++i)
#pragma unroll
          for (int j = 0; j < 4; ++j)
            acc[i][j] = __builtin_amdgcn_mfma_f32_16x16x32_bf16(af[i], bfr[j], acc[i][j], 0, 0, 0);
      }
    }
#pragma unroll
    for (int i = 0; i < 4; ++i) {
#pragma unroll
      for (int j = 0; j < 4; ++j) {
        const int mb = m0 + wm * 64 + i * 16 + g * 4;
        const int nn = nl0 + wn * 64 + j * 16 + c;
        const f32x4 a = acc[i][j];
        if (wid == 0) {
#pragma unroll
          for (int r = 0; r < 4; ++r) qb[(size_t)(mb + r) * CS + nn] = f2bf(a[r] * 0.125f);
        } else if (wid == 1) {
#pragma unroll
          for (int r = 0; r < 4; ++r) kb[(size_t)(mb + r) * CS + nn] = f2bf(a[r]);
        } else if (wid == 2) {
          ushort4 pk;
          pk.x = f2bf(a[0]); pk.y = f2bf(a[1]); pk.z = f2bf(a[2]); pk.w = f2bf(a[3]);
          *(ushort4*)&vt[(size_t)nn * LQ + mb] = pk;
        } else {
          const float bb = bg[nn];
#pragma unroll
          for (int r = 0; r < 4; ++r) gpre[(size_t)(mb + r) * CS + nn] = a[r] + bb;
        }
      }
    }
  } else {
    // ---- pair-bias path: block = 4 i-rows x 64 j, one thread per (i,j) pair ----
    unsigned short (*z_lds)[72] = (unsigned short (*)[72])sm;  // 256 x 72 bf16
    const int pid = bid - 192;
    const int i4 = pid >> 4;            // 0..255
    const int i0 = i4 * 4;
    const int jtg = pid & 15;           // j-64-block = jtg
    const int j0 = jtg * 64;
    const int ii = t >> 6;              // wave = i offset
    const int jj = t & 63;              // pair j within tile; also lane
    const int g = jj >> 4, cc = jj & 15;

    if (t < CZ) { zgL[t] = zg[t]; zbL[t] = zb[t]; }
    __syncthreads();

    const float* src = pair + ((size_t)(i0 + ii) * LQ + (j0 + jj)) * CZ;
    float x[64];
#pragma unroll
    for (int u = 0; u < 16; ++u) *(f4*)&x[u * 4] = ((const f4*)src)[u];
    float s1 = 0.f, s2 = 0.f;
#pragma unroll
    for (int c2 = 0; c2 < 64; ++c2) { s1 += x[c2]; s2 += x[c2] * x[c2]; }
    const float mu = s1 * (1.f / CZ);
    const float var = s2 * (1.f / CZ) - mu * mu;
    const float rs = rsqrtf(var + 1e-5f);
#pragma unroll
    for (int u = 0; u < 16; ++u) {
      const f4 g4 = *(const f4*)&zgL[u * 4];
      const f4 b4 = *(const f4*)&zbL[u * 4];
      ushort4 zn;
      zn.x = f2bf((x[u * 4 + 0] - mu) * rs * g4.x + b4.x);
      zn.y = f2bf((x[u * 4 + 1] - mu) * rs * g4.y + b4.y);
      zn.z = f2bf((x[u * 4 + 2] - mu) * rs * g4.z + b4.z);
      zn.w = f2bf((x[u * 4 + 3] - mu) * rs * g4.w + b4.w);
      *(ushort4*)&z_lds[t][u * 4] = zn;
    }

    // Wb B-fragment (per lane, col = head cc, zero-pad heads >= 12)
    bf16x8 wfrag[2];
#pragma unroll
    for (int kk = 0; kk < 2; ++kk) {
#pragma unroll
      for (int u = 0; u < 8; ++u) {
        const int ch = kk * 32 + g * 8 + u;
        const float wv = (cc < NH) ? Wb[ch * NH + cc] : 0.f;
        wfrag[kk][u] = (short)f2bf(wv);
      }
    }
    __syncthreads();

    f32x4 dfrag[4];
#pragma unroll
    for (int pg = 0; pg < 4; ++pg) {
      const bf16x8 a0 = *(const bf16x8*)&z_lds[ii * 64 + pg * 16 + cc][g * 8];
      const bf16x8 a1 = *(const bf16x8*)&z_lds[ii * 64 + pg * 16 + cc][32 + g * 8];
      f32x4 dd = (f32x4){0.f, 0.f, 0.f, 0.f};
      dd = __builtin_amdgcn_mfma_f32_16x16x32_bf16(a0, wfrag[0], dd, 0, 0, 0);
      dd = __builtin_amdgcn_mfma_f32_16x16x32_bf16(a1, wfrag[1], dd, 0, 0, 0);
      dfrag[pg] = dd;
    }

    if (cc < NH) {
      const int gi = i0 >> 4;        // block never crosses a 16-row boundary
      const int g_a = i4 & 3;
      const int r_i = ii;
      const size_t X = (((size_t)cc * 64 + gi) * 16 + jtg);
      const size_t base = X * 1024 + (size_t)g_a * 64 + r_i;
#pragma unroll
      for (int pg = 0; pg < 4; ++pg)
#pragma unroll
        for (int r = 0; r < 4; ++r)
          biasF[base + pg * 256 + (g * 4 + r) * 4] = f2bf(dfrag[pg][r]);
    }
  }
}

// ============ kernel 3: MFMA flash attention, j-split x2, double-buffered ============
__global__ __launch_bounds__(256) void attn_k(
    const unsigned short* __restrict__ q, const unsigned short* __restrict__ k,
    const unsigned short* __restrict__ vt, const unsigned short* __restrict__ biasF,
    float* __restrict__ Opart, float* __restrict__ ml) {
  __shared__ __align__(16) unsigned short Qs[64][88];
  __shared__ __align__(16) unsigned short Ks[2][64][88];
  __shared__ __align__(16) unsigned short Vts[2][64][88];
  __shared__ __align__(16) unsigned short Ps[4][16][88];
  const int bx = blockIdx.x, h = blockIdx.y, z = blockIdx.z;
  const int i0 = bx * 64;
  const int jb = z * 512;
  const int t = threadIdx.x;
  const int w = t >> 6, lane = t & 63, g = lane >> 4, c = lane & 15;
  const int sr = t >> 2, sc = (t & 3) * 16;

  // stage Q, K/V tile 0
#pragma unroll
  for (int u = 0; u < 2; ++u) {
    *(uint4*)&Qs[sr][sc + u * 8]     = *(const uint4*)&q[(size_t)(i0 + sr) * CS + h * HD + sc + u * 8];
    *(uint4*)&Ks[0][sr][sc + u * 8]  = *(const uint4*)&k[(size_t)(jb + sr) * CS + h * HD + sc + u * 8];
    *(uint4*)&Vts[0][sr][sc + u * 8] = *(const uint4*)&vt[(size_t)(h * HD + sr) * LQ + jb + sc + u * 8];
  }
  // bias fragment base (ushort index); jt stride = 1024, nb stride = 256
  const size_t bbase = ((((size_t)h * 64 + (bx * 4 + w)) * 16 + (size_t)z * 8) * 4) * 256 + lane * 4;
  ushort4 bcur[4];
#pragma unroll
  for (int nb = 0; nb < 4; ++nb) bcur[nb] = *(const ushort4*)&biasF[bbase + nb * 256];
  __syncthreads();

  const bf16x8 aq0 = *(const bf16x8*)&Qs[w * 16 + c][g * 8];
  const bf16x8 aq1 = *(const bf16x8*)&Qs[w * 16 + c][32 + g * 8];

  f32x4 acc_o[4];
#pragma unroll
  for (int nb = 0; nb < 4; ++nb) acc_o[nb] = (f32x4){0.f, 0.f, 0.f, 0.f};
  float m_run[4] = {-1e30f, -1e30f, -1e30f, -1e30f};
  float l_run[4] = {0.f, 0.f, 0.f, 0.f};

  for (int jt = 0; jt < 8; ++jt) {
    const int cur = jt & 1;
    uint4 kr0, kr1, vr0, vr1;
    ushort4 bnx[4];
    if (jt < 7) {  // prefetch next tile into registers (T14 async-stage)
      const int jn = jb + (jt + 1) * 64;
      kr0 = *(const uint4*)&k[(size_t)(jn + sr) * CS + h * HD + sc];
      kr1 = *(const uint4*)&k[(size_t)(jn + sr) * CS + h * HD + sc + 8];
      vr0 = *(const uint4*)&vt[(size_t)(h * HD + sr) * LQ + jn + sc];
      vr1 = *(const uint4*)&vt[(size_t)(h * HD + sr) * LQ + jn + sc + 8];
#pragma unroll
      for (int nb = 0; nb < 4; ++nb)
        bnx[nb] = *(const ushort4*)&biasF[bbase + (size_t)(jt + 1) * 1024 + nb * 256];
    }

    // S = bias + (Q/8) K^T
    f32x4 sa[4];
#pragma unroll
    for (int nb = 0; nb < 4; ++nb) {
      f32x4 ci;
      ci[0] = bf2f(bcur[nb].x); ci[1] = bf2f(bcur[nb].y);
      ci[2] = bf2f(bcur[nb].z); ci[3] = bf2f(bcur[nb].w);
      const bf16x8 b0 = *(const bf16x8*)&Ks[cur][nb * 16 + c][g * 8];
      const bf16x8 b1 = *(const bf16x8*)&Ks[cur][nb * 16 + c][32 + g * 8];
      ci = __builtin_amdgcn_mfma_f32_16x16x32_bf16(aq0, b0, ci, 0, 0, 0);
      ci = __builtin_amdgcn_mfma_f32_16x16x32_bf16(aq1, b1, ci, 0, 0, 0);
      sa[nb] = ci;
    }

    // online softmax
    float mt[4];
#pragma unroll
    for (int r = 0; r < 4; ++r) {
      float v = fmaxf(fmaxf(sa[0][r], sa[1][r]), fmaxf(sa[2][r], sa[3][r]));
      v = fmaxf(v, __shfl_xor(v, 1));
      v = fmaxf(v, __shfl_xor(v, 2));
      v = fmaxf(v, __shfl_xor(v, 4));
      v = fmaxf(v, __shfl_xor(v, 8));
      mt[r] = v;
    }
    float scale[4], ps[4];
#pragma unroll
    for (int r = 0; r < 4; ++r) {
      const float mn = fmaxf(m_run[r], mt[r]);
      scale[r] = __expf(m_run[r] - mn);
      m_run[r] = mn;
      ps[r] = 0.f;
    }
#pragma unroll
    for (int nb = 0; nb < 4; ++nb) {
#pragma unroll
      for (int r = 0; r < 4; ++r) {
        const float p = __expf(sa[nb][r] - m_run[r]);
        ps[r] += p;
        Ps[w][g * 4 + r][nb * 16 + c] = f2bf(p);
      }
    }
#pragma unroll
    for (int r = 0; r < 4; ++r) {
      float v = ps[r];
      v += __shfl_xor(v, 1);
      v += __shfl_xor(v, 2);
      v += __shfl_xor(v, 4);
      v += __shfl_xor(v, 8);
      l_run[r] = l_run[r] * scale[r] + v;
#pragma unroll
      for (int nb = 0; nb < 4; ++nb) acc_o[nb][r] *= scale[r];
    }

    // O += P @ V (per-wave Ps, same-wave ordering via lgkmcnt)
#pragma unroll
    for (int kb = 0; kb < 2; ++kb) {
      const bf16x8 pa = *(const bf16x8*)&Ps[w][c][kb * 32 + g * 8];
#pragma unroll
      for (int nb = 0; nb < 4; ++nb) {
        const bf16x8 bv = *(const bf16x8*)&Vts[cur][nb * 16 + c][kb * 32 + g * 8];
        acc_o[nb] = __builtin_amdgcn_mfma_f32_16x16x32_bf16(pa, bv, acc_o[nb], 0, 0, 0);
      }
    }

    if (jt < 7) {  // write prefetched tile to the other buffer; one barrier per iter
      *(uint4*)&Ks[cur ^ 1][sr][sc]      = kr0;
      *(uint4*)&Ks[cur ^ 1][sr][sc + 8]  = kr1;
      *(uint4*)&Vts[cur ^ 1][sr][sc]     = vr0;
      *(uint4*)&Vts[cur ^ 1][sr][sc + 8] = vr1;
      __syncthreads();
#pragma unroll
      for (int nb = 0; nb < 4; ++nb) bcur[nb] = bnx[nb];
    }
  }

  // store partial (unnormalized O, m, l)
  const size_t rowb = (size_t)(z * NH + h) * LQ + i0 + w * 16 + g * 4;
#pragma unroll
  for (int nb = 0; nb < 4; ++nb)
#pragma unroll
    for (int r = 0; r < 4; ++r)
      Opart[(rowb + r) * HD + nb * 16 + c] = acc_o[nb][r];
  if (c == 0) {
#pragma unroll
    for (int r = 0; r < 4; ++r) {
      ml[(rowb + r) * 2]     = m_run[r];
      ml[(rowb + r) * 2 + 1] = l_run[r];
    }
  }
}

// ============ kernel 4: combine the two j-halves ============
__global__ __launch_bounds__(256) void combine_k(
    const float* __restrict__ Opart, const float* __restrict__ ml,
    unsigned short* __restrict__ attno) {
  const int t = threadIdx.x;
  const int row = blockIdx.x * 4 + (t >> 6);   // 0..12287 = h*1024 + i
  const int d = t & 63;
  const int h = row >> 10, i = row & 1023;
  const size_t r0 = (size_t)h * LQ + i;
  const size_t r1 = (size_t)(NH + h) * LQ + i;
  const float m0 = ml[r0 * 2], l0 = ml[r0 * 2 + 1];
  const float m1 = ml[r1 * 2], l1 = ml[r1 * 2 + 1];
  const float M = fmaxf(m0, m1);
  const float a0 = __expf(m0 - M), a1 = __expf(m1 - M);
  const float L = a0 * l0 + a1 * l1;
  const float o = (a0 * Opart[r0 * HD + d] + a1 * Opart[r1 * HD + d]) / L;
  attno[(size_t)i * CS + h * HD + d] = f2bf(o);
}

// ============ kernel 5: final GEMM (64x128 tiles) + gated residual ============
__global__ __launch_bounds__(256) void gemm_final_k(
    const unsigned short* __restrict__ A, const unsigned short* __restrict__ wt,
    const float* __restrict__ bout, const float* __restrict__ single,
    const float* __restrict__ gpre, float* __restrict__ out) {
  __shared__ __align__(16) unsigned short As[64][88];
  __shared__ __align__(16) unsigned short Bs[128][88];
  const int t = threadIdx.x;
  const int wave = t >> 6, lane = t & 63, g = lane >> 4, c = lane & 15;
  const int wm = wave >> 1, wn = wave & 1;
  const int m0 = blockIdx.y * 64;
  const int nl0 = blockIdx.x * 128;
  const unsigned short* B = wt + (size_t)4 * CS * CS;  // Wout^T

  f32x4 acc[2][4];
#pragma unroll
  for (int i = 0; i < 2; ++i)
#pragma unroll
    for (int j = 0; j < 4; ++j) acc[i][j] = (f32x4){0.f, 0.f, 0.f, 0.f};

  const int sra = t >> 2, sha = (t & 3) * 16;
  const int srb = t >> 1, shb = (t & 1) * 32;
  for (int kt = 0; kt < CS; kt += 64) {
    __syncthreads();
#pragma unroll
    for (int u = 0; u < 2; ++u)
      *(uint4*)&As[sra][sha + u * 8] = *(const uint4*)&A[(size_t)(m0 + sra) * CS + kt + sha + u * 8];
#pragma unroll
    for (int u = 0; u < 4; ++u)
      *(uint4*)&Bs[srb][shb + u * 8] = *(const uint4*)&B[(size_t)(nl0 + srb) * CS + kt + shb + u * 8];
    __syncthreads();
#pragma unroll
    for (int kk = 0; kk < 64; kk += 32) {
      bf16x8 af[2], bfr[4];
#pragma unroll
      for (int i = 0; i < 2; ++i) af[i] = *(const bf16x8*)&As[wm * 32 + i * 16 + c][kk + g * 8];
#pragma unroll
      for (int j = 0; j < 4; ++j) bfr[j] = *(const bf16x8*)&Bs[wn * 64 + j * 16 + c][kk + g * 8];
#pragma unroll
      for (int i = 0; i < 2; ++i)
#pragma unroll
        for (int j = 0; j < 4; ++j)
          acc[i][j] = __builtin_amdgcn_mfma_f32_16x16x32_bf16(af[i], bfr[j], acc[i][j], 0, 0, 0);
    }
  }

#pragma unroll
  for (int i = 0; i < 2; ++i) {
#pragma unroll
    for (int j = 0; j < 4; ++j) {
      const int mb = m0 + wm * 32 + i * 16 + g * 4;
      const int nn = nl0 + wn * 64 + j * 16 + c;
      const float bb = bout[nn];
      const f32x4 a = acc[i][j];
#pragma unroll
      for (int r = 0; r < 4; ++r) {
        const size_t idx = (size_t)(mb + r) * CS + nn;
        const float gate = 1.f / (1.f + __expf(-gpre[idx]));
        out[idx] = single[idx] + gate * (a[r] + bb);
      }
    }
  }
}

extern "C" void kernel_launch(void* const* d_in, const int* in_sizes, int n_in,
                              void* d_out, int out_size, void* d_ws, size_t ws_size,
                              hipStream_t stream) {
  const float* single = (const float*)d_in[0];
  const float* pair   = (const float*)d_in[1];
  const float* ln_s_g = (const float*)d_in[2];
  const float* ln_s_b = (const float*)d_in[3];
  const float* ln_z_g = (const float*)d_in[4];
  const float* ln_z_b = (const float*)d_in[5];
  const float* Wq     = (const float*)d_in[6];
  const float* Wk     = (const float*)d_in[7];
  const float* Wv     = (const float*)d_in[8];
  const float* Wb     = (const float*)d_in[9];
  const float* Wout   = (const float*)d_in[10];
  const float* bout   = (const float*)d_in[11];
  const float* Wgate  = (const float*)d_in[12];
  const float* bgate  = (const float*)d_in[13];
  float* out = (float*)d_out;

  unsigned short* s_bf  = (unsigned short*)d_ws;
  unsigned short* wt    = s_bf  + (size_t)LQ * CS;
  unsigned short* q_bf  = wt    + (size_t)5 * CS * CS;
  unsigned short* k_bf  = q_bf  + (size_t)LQ * CS;
  unsigned short* vt_bf = k_bf  + (size_t)LQ * CS;
  unsigned short* attno = vt_bf + (size_t)CS * LQ;
  unsigned short* biasF = attno + (size_t)LQ * CS;
  float* gpre  = (float*)(biasF + (size_t)NH * LQ * LQ);
  float* Opart = gpre  + (size_t)LQ * CS;
  float* mlw   = Opart + (size_t)2 * NH * LQ * HD;

  hipLaunchKernelGGL(ln_wconv_k, dim3(LQ + 720), dim3(256), 0, stream,
                     single, ln_s_g, ln_s_b, s_bf, Wq, Wk, Wv, Wgate, Wout, wt);
  hipLaunchKernelGGL(qkvg_pair_k, dim3(192 + 4096), dim3(256), 0, stream,
                     s_bf, wt, bgate, q_bf, k_bf, vt_bf, gpre,
                     pair, ln_z_g, ln_z_b, Wb, biasF);
  hipLaunchKernelGGL(attn_k, dim3(16, NH, 2), dim3(256), 0, stream,
                     q_bf, k_bf, vt_bf, biasF, Opart, mlw);
  hipLaunchKernelGGL(combine_k, dim3(3072), dim3(256), 0, stream,
                     Opart, mlw, attno);
  hipLaunchKernelGGL(gemm_final_k, dim3(6, 16), dim3(256), 0, stream,
                     attno, wt, bout, single, gpre, out);
}

// Round 4
// 125.676 us; speedup vs baseline: 3.6916x; 1.3238x over previous
//
#include <hip/hip_runtime.h>

#define LQ 1024
#define CS 768
#define CZ 64
#define NH 12
#define HD 64

typedef float4 f4;
using bf16x8 = __attribute__((ext_vector_type(8))) short;
using f32x4  = __attribute__((ext_vector_type(4))) float;

static __device__ __forceinline__ unsigned short f2bf(float f) {
  unsigned int u = __float_as_uint(f);
  u += 0x7fffu + ((u >> 16) & 1u);
  return (unsigned short)(u >> 16);
}
static __device__ __forceinline__ float bf2f(unsigned short b) {
  return __uint_as_float(((unsigned int)b) << 16);
}

// ============ kernel 1: ln_single + weight convert/transpose (fused) ============
__global__ __launch_bounds__(256) void ln_wconv_k(
    const float* __restrict__ x, const float* __restrict__ g,
    const float* __restrict__ b, unsigned short* __restrict__ s_out,
    const float* __restrict__ Wq, const float* __restrict__ Wk,
    const float* __restrict__ Wv, const float* __restrict__ Wg,
    const float* __restrict__ Wo, unsigned short* __restrict__ wt) {
  const int bid = blockIdx.x;
  const int t = threadIdx.x;
  if (bid < LQ) {
    const int row = bid;
    const float* xr = x + (size_t)row * CS;
    float v0 = xr[t], v1 = xr[t + 256], v2 = xr[t + 512];
    float s1 = v0 + v1 + v2;
    float s2 = v0 * v0 + v1 * v1 + v2 * v2;
#pragma unroll
    for (int m = 1; m < 64; m <<= 1) {
      s1 += __shfl_xor(s1, m);
      s2 += __shfl_xor(s2, m);
    }
    __shared__ float r1[4], r2[4];
    const int wid = t >> 6;
    if ((t & 63) == 0) { r1[wid] = s1; r2[wid] = s2; }
    __syncthreads();
    s1 = r1[0] + r1[1] + r1[2] + r1[3];
    s2 = r2[0] + r2[1] + r2[2] + r2[3];
    const float mu = s1 * (1.f / CS);
    const float var = s2 * (1.f / CS) - mu * mu;
    const float rs = rsqrtf(var + 1e-5f);
    s_out[(size_t)row * CS + t]       = f2bf((v0 - mu) * rs * g[t]       + b[t]);
    s_out[(size_t)row * CS + t + 256] = f2bf((v1 - mu) * rs * g[t + 256] + b[t + 256]);
    s_out[(size_t)row * CS + t + 512] = f2bf((v2 - mu) * rs * g[t + 512] + b[t + 512]);
  } else {
    int r = bid - LQ;                    // 0..719
    const int bz = r / 144; r %= 144;
    const int n0 = (r % 12) * 64, k0 = (r / 12) * 64;
    const float* W;
    switch (bz) {
      case 0: W = Wq; break;
      case 1: W = Wk; break;
      case 2: W = Wv; break;
      case 3: W = Wg; break;
      default: W = Wo; break;
    }
    unsigned short* o = wt + (size_t)bz * CS * CS;
    __shared__ float T[64][68];
    {
      const int rr = t >> 4, c = (t & 15) * 4;
#pragma unroll
      for (int u = 0; u < 4; ++u) {
        const f4 v = *(const f4*)&W[(size_t)(k0 + rr + u * 16) * CS + n0 + c];
        *(f4*)&T[rr + u * 16][c] = v;
      }
    }
    __syncthreads();
    {
      const int rn = t >> 2, ck = (t & 3) * 16;
      __align__(16) unsigned short tmp[16];
#pragma unroll
      for (int u = 0; u < 16; ++u) tmp[u] = f2bf(T[ck + u][rn]);
      unsigned short* dst = &o[(size_t)(n0 + rn) * CS + k0 + ck];
      *(uint4*)dst = ((const uint4*)tmp)[0];
      *(uint4*)(dst + 8) = ((const uint4*)tmp)[1];
    }
  }
}

// ============ kernel 2: QKVG GEMM (192 blocks) || LDS-free pair-bias MFMA (1024 blocks) ============
// biasF layout (attn-fragment): for element (h, i, j):
//   flat = (((h*64 + (i>>4))*16 + (j>>6))*4 + ((j>>4)&3))*256
//          + ((i>>2)&3)*64 + (j&15)*4 + (i&3)
__global__ __launch_bounds__(256) void qkvg_pair_k(
    const unsigned short* __restrict__ s, const unsigned short* __restrict__ wt,
    const float* __restrict__ bg,
    unsigned short* __restrict__ qb, unsigned short* __restrict__ kb,
    unsigned short* __restrict__ vt, float* __restrict__ gpre,
    const float* __restrict__ pair, const float* __restrict__ zg,
    const float* __restrict__ zb, const float* __restrict__ Wb,
    unsigned short* __restrict__ biasF) {
  __shared__ __align__(16) unsigned short sm[2 * 128 * 88];  // GEMM path only
  const int bid = blockIdx.x;
  const int t = threadIdx.x;

  if (bid < 192) {
    // ---- QKVG GEMM path (unchanged from R3) ----
    unsigned short (*As)[88] = (unsigned short (*)[88])sm;
    unsigned short (*Bs)[88] = (unsigned short (*)[88])(sm + 128 * 88);
    const int wave = t >> 6, lane = t & 63, g = lane >> 4, c = lane & 15;
    const int wm = wave >> 1, wn = wave & 1;
    const int bx = bid % 24, by = bid / 24;
    const int m0 = by * 128;
    const int wid = bx / 6;
    const int nl0 = (bx % 6) * 128;
    const unsigned short* B = wt + (size_t)wid * CS * CS;

    f32x4 acc[4][4];
#pragma unroll
    for (int i = 0; i < 4; ++i)
#pragma unroll
      for (int j = 0; j < 4; ++j) acc[i][j] = (f32x4){0.f, 0.f, 0.f, 0.f};

    const int sr = t >> 1, sh = (t & 1) * 32;
    for (int kt = 0; kt < CS; kt += 64) {
      __syncthreads();
#pragma unroll
      for (int u = 0; u < 4; ++u) {
        *(uint4*)&As[sr][sh + u * 8] = *(const uint4*)&s[(size_t)(m0 + sr) * CS + kt + sh + u * 8];
        *(uint4*)&Bs[sr][sh + u * 8] = *(const uint4*)&B[(size_t)(nl0 + sr) * CS + kt + sh + u * 8];
      }
      __syncthreads();
#pragma unroll
      for (int kk = 0; kk < 64; kk += 32) {
        bf16x8 af[4], bfr[4];
#pragma unroll
        for (int i = 0; i < 4; ++i) af[i] = *(const bf16x8*)&As[wm * 64 + i * 16 + c][kk + g * 8];
#pragma unroll
        for (int j = 0; j < 4; ++j) bfr[j] = *(const bf16x8*)&Bs[wn * 64 + j * 16 + c][kk + g * 8];
#pragma unroll
        for (int i = 0; i < 4; ++i)
#pragma unroll
          for (int j = 0; j < 4; ++j)
            acc[i][j] = __builtin_amdgcn_mfma_f32_16x16x32_bf16(af[i], bfr[j], acc[i][j], 0, 0, 0);
      }
    }
#pragma unroll
    for (int i = 0; i < 4; ++i) {
#pragma unroll
      for (int j = 0; j < 4; ++j) {
        const int mb = m0 + wm * 64 + i * 16 + g * 4;
        const int nn = nl0 + wn * 64 + j * 16 + c;
        const f32x4 a = acc[i][j];
        if (wid == 0) {
#pragma unroll
          for (int r = 0; r < 4; ++r) qb[(size_t)(mb + r) * CS + nn] = f2bf(a[r] * 0.125f);
        } else if (wid == 1) {
#pragma unroll
          for (int r = 0; r < 4; ++r) kb[(size_t)(mb + r) * CS + nn] = f2bf(a[r]);
        } else if (wid == 2) {
          ushort4 pk;
          pk.x = f2bf(a[0]); pk.y = f2bf(a[1]); pk.z = f2bf(a[2]); pk.w = f2bf(a[3]);
          *(ushort4*)&vt[(size_t)nn * LQ + mb] = pk;
        } else {
          const float bb = bg[nn];
#pragma unroll
          for (int r = 0; r < 4; ++r) gpre[(size_t)(mb + r) * CS + nn] = a[r] + bb;
        }
      }
    }
  } else {
    // ---- pair-bias path: LDS-free, register-fragment MFMA ----
    // block = 4 i-rows x 256 j. wave handles 4i x 64j; MFMA step = 4i x 4j pairs.
    const int pid = bid - 192;
    const int i0 = (pid >> 2) * 4;
    const int j0 = (pid & 3) * 256;
    const int w = t >> 6, lane = t & 63, g = lane >> 4, c = lane & 15;

    // hoisted LN gamma/beta registers for this lane's channels (g*8.. / 32+g*8..)
    float zgr[16], zbr[16];
    *(f4*)&zgr[0]  = *(const f4*)&zg[g * 8];
    *(f4*)&zgr[4]  = *(const f4*)&zg[g * 8 + 4];
    *(f4*)&zgr[8]  = *(const f4*)&zg[32 + g * 8];
    *(f4*)&zgr[12] = *(const f4*)&zg[32 + g * 8 + 4];
    *(f4*)&zbr[0]  = *(const f4*)&zb[g * 8];
    *(f4*)&zbr[4]  = *(const f4*)&zb[g * 8 + 4];
    *(f4*)&zbr[8]  = *(const f4*)&zb[32 + g * 8];
    *(f4*)&zbr[12] = *(const f4*)&zb[32 + g * 8 + 4];

    // hoisted Wb B-fragment: col = head c, k = channel
    bf16x8 wf0, wf1;
    const int csafe = (c < NH) ? c : 0;
#pragma unroll
    for (int u = 0; u < 8; ++u) {
      const float w0 = (c < NH) ? Wb[(g * 8 + u) * NH + csafe] : 0.f;
      const float w1 = (c < NH) ? Wb[(32 + g * 8 + u) * NH + csafe] : 0.f;
      wf0[u] = (short)f2bf(w0);
      wf1[u] = (short)f2bf(w1);
    }

    const int il = c & 3, jl = c >> 2;      // lane's pair: row i0+il, col jw+jl
    const int irow = i0 + il;
    const int gi = i0 >> 4, ga = (i0 >> 2) & 3;
    const size_t hd_base = ((size_t)gi * 16) * 4 * 256 + (size_t)ga * 64;

    for (int it = 0; it < 16; ++it) {
      const int jw = j0 + w * 64 + it * 4;
      const float* src = pair + ((size_t)irow * LQ + (jw + jl)) * CZ;
      float x0[8], x1[8];
      *(f4*)&x0[0] = *(const f4*)&src[g * 8];
      *(f4*)&x0[4] = *(const f4*)&src[g * 8 + 4];
      *(f4*)&x1[0] = *(const f4*)&src[32 + g * 8];
      *(f4*)&x1[4] = *(const f4*)&src[32 + g * 8 + 4];

      // tree-reduced partial sums (16 ch), then 4-lane reduce across g
      float s1 = (((x0[0] + x0[1]) + (x0[2] + x0[3])) + ((x0[4] + x0[5]) + (x0[6] + x0[7])))
               + (((x1[0] + x1[1]) + (x1[2] + x1[3])) + ((x1[4] + x1[5]) + (x1[6] + x1[7])));
      float s2 = (((x0[0]*x0[0] + x0[1]*x0[1]) + (x0[2]*x0[2] + x0[3]*x0[3]))
               +  ((x0[4]*x0[4] + x0[5]*x0[5]) + (x0[6]*x0[6] + x0[7]*x0[7])))
               + (((x1[0]*x1[0] + x1[1]*x1[1]) + (x1[2]*x1[2] + x1[3]*x1[3]))
               +  ((x1[4]*x1[4] + x1[5]*x1[5]) + (x1[6]*x1[6] + x1[7]*x1[7])));
      s1 += __shfl_xor(s1, 16); s1 += __shfl_xor(s1, 32);
      s2 += __shfl_xor(s2, 16); s2 += __shfl_xor(s2, 32);
      const float mu = s1 * (1.f / CZ);
      const float var = s2 * (1.f / CZ) - mu * mu;
      const float rs = rsqrtf(var + 1e-5f);

      bf16x8 a0, a1;
#pragma unroll
      for (int u = 0; u < 8; ++u) {
        a0[u] = (short)f2bf((x0[u] - mu) * rs * zgr[u] + zbr[u]);
        a1[u] = (short)f2bf((x1[u] - mu) * rs * zgr[8 + u] + zbr[8 + u]);
      }

      f32x4 dd = (f32x4){0.f, 0.f, 0.f, 0.f};
      dd = __builtin_amdgcn_mfma_f32_16x16x32_bf16(a0, wf0, dd, 0, 0, 0);
      dd = __builtin_amdgcn_mfma_f32_16x16x32_bf16(a1, wf1, dd, 0, 0, 0);

      // D: lane (g,c) holds pairs (i0+r, jw+g), head c -> one ushort4 store
      if (c < NH) {
        const int jj = jw + g;
        const size_t base = ((size_t)c * 64) * 16384
                          + hd_base
                          + (size_t)(jj >> 6) * 1024
                          + (size_t)((jj >> 4) & 3) * 256
                          + (jj & 15) * 4;
        ushort4 st;
        st.x = f2bf(dd[0]); st.y = f2bf(dd[1]); st.z = f2bf(dd[2]); st.w = f2bf(dd[3]);
        *(ushort4*)&biasF[base] = st;
      }
    }
  }
}

// ============ kernel 3: MFMA flash attention, j-split x2, double-buffered ============
__global__ __launch_bounds__(256) void attn_k(
    const unsigned short* __restrict__ q, const unsigned short* __restrict__ k,
    const unsigned short* __restrict__ vt, const unsigned short* __restrict__ biasF,
    float* __restrict__ Opart, float* __restrict__ ml) {
  __shared__ __align__(16) unsigned short Qs[64][88];
  __shared__ __align__(16) unsigned short Ks[2][64][88];
  __shared__ __align__(16) unsigned short Vts[2][64][88];
  __shared__ __align__(16) unsigned short Ps[4][16][88];
  const int bx = blockIdx.x, h = blockIdx.y, z = blockIdx.z;
  const int i0 = bx * 64;
  const int jb = z * 512;
  const int t = threadIdx.x;
  const int w = t >> 6, lane = t & 63, g = lane >> 4, c = lane & 15;
  const int sr = t >> 2, sc = (t & 3) * 16;

#pragma unroll
  for (int u = 0; u < 2; ++u) {
    *(uint4*)&Qs[sr][sc + u * 8]     = *(const uint4*)&q[(size_t)(i0 + sr) * CS + h * HD + sc + u * 8];
    *(uint4*)&Ks[0][sr][sc + u * 8]  = *(const uint4*)&k[(size_t)(jb + sr) * CS + h * HD + sc + u * 8];
    *(uint4*)&Vts[0][sr][sc + u * 8] = *(const uint4*)&vt[(size_t)(h * HD + sr) * LQ + jb + sc + u * 8];
  }
  const size_t bbase = ((((size_t)h * 64 + (bx * 4 + w)) * 16 + (size_t)z * 8) * 4) * 256 + lane * 4;
  ushort4 bcur[4];
#pragma unroll
  for (int nb = 0; nb < 4; ++nb) bcur[nb] = *(const ushort4*)&biasF[bbase + nb * 256];
  __syncthreads();

  const bf16x8 aq0 = *(const bf16x8*)&Qs[w * 16 + c][g * 8];
  const bf16x8 aq1 = *(const bf16x8*)&Qs[w * 16 + c][32 + g * 8];

  f32x4 acc_o[4];
#pragma unroll
  for (int nb = 0; nb < 4; ++nb) acc_o[nb] = (f32x4){0.f, 0.f, 0.f, 0.f};
  float m_run[4] = {-1e30f, -1e30f, -1e30f, -1e30f};
  float l_run[4] = {0.f, 0.f, 0.f, 0.f};

  for (int jt = 0; jt < 8; ++jt) {
    const int cur = jt & 1;
    uint4 kr0, kr1, vr0, vr1;
    ushort4 bnx[4];
    if (jt < 7) {
      const int jn = jb + (jt + 1) * 64;
      kr0 = *(const uint4*)&k[(size_t)(jn + sr) * CS + h * HD + sc];
      kr1 = *(const uint4*)&k[(size_t)(jn + sr) * CS + h * HD + sc + 8];
      vr0 = *(const uint4*)&vt[(size_t)(h * HD + sr) * LQ + jn + sc];
      vr1 = *(const uint4*)&vt[(size_t)(h * HD + sr) * LQ + jn + sc + 8];
#pragma unroll
      for (int nb = 0; nb < 4; ++nb)
        bnx[nb] = *(const ushort4*)&biasF[bbase + (size_t)(jt + 1) * 1024 + nb * 256];
    }

    f32x4 sa[4];
#pragma unroll
    for (int nb = 0; nb < 4; ++nb) {
      f32x4 ci;
      ci[0] = bf2f(bcur[nb].x); ci[1] = bf2f(bcur[nb].y);
      ci[2] = bf2f(bcur[nb].z); ci[3] = bf2f(bcur[nb].w);
      const bf16x8 b0 = *(const bf16x8*)&Ks[cur][nb * 16 + c][g * 8];
      const bf16x8 b1 = *(const bf16x8*)&Ks[cur][nb * 16 + c][32 + g * 8];
      ci = __builtin_amdgcn_mfma_f32_16x16x32_bf16(aq0, b0, ci, 0, 0, 0);
      ci = __builtin_amdgcn_mfma_f32_16x16x32_bf16(aq1, b1, ci, 0, 0, 0);
      sa[nb] = ci;
    }

    float mt[4];
#pragma unroll
    for (int r = 0; r < 4; ++r) {
      float v = fmaxf(fmaxf(sa[0][r], sa[1][r]), fmaxf(sa[2][r], sa[3][r]));
      v = fmaxf(v, __shfl_xor(v, 1));
      v = fmaxf(v, __shfl_xor(v, 2));
      v = fmaxf(v, __shfl_xor(v, 4));
      v = fmaxf(v, __shfl_xor(v, 8));
      mt[r] = v;
    }
    float scale[4], ps[4];
#pragma unroll
    for (int r = 0; r < 4; ++r) {
      const float mn = fmaxf(m_run[r], mt[r]);
      scale[r] = __expf(m_run[r] - mn);
      m_run[r] = mn;
      ps[r] = 0.f;
    }
#pragma unroll
    for (int nb = 0; nb < 4; ++nb) {
#pragma unroll
      for (int r = 0; r < 4; ++r) {
        const float p = __expf(sa[nb][r] - m_run[r]);
        ps[r] += p;
        Ps[w][g * 4 + r][nb * 16 + c] = f2bf(p);
      }
    }
#pragma unroll
    for (int r = 0; r < 4; ++r) {
      float v = ps[r];
      v += __shfl_xor(v, 1);
      v += __shfl_xor(v, 2);
      v += __shfl_xor(v, 4);
      v += __shfl_xor(v, 8);
      l_run[r] = l_run[r] * scale[r] + v;
#pragma unroll
      for (int nb = 0; nb < 4; ++nb) acc_o[nb][r] *= scale[r];
    }

#pragma unroll
    for (int kb = 0; kb < 2; ++kb) {
      const bf16x8 pa = *(const bf16x8*)&Ps[w][c][kb * 32 + g * 8];
#pragma unroll
      for (int nb = 0; nb < 4; ++nb) {
        const bf16x8 bv = *(const bf16x8*)&Vts[cur][nb * 16 + c][kb * 32 + g * 8];
        acc_o[nb] = __builtin_amdgcn_mfma_f32_16x16x32_bf16(pa, bv, acc_o[nb], 0, 0, 0);
      }
    }

    if (jt < 7) {
      *(uint4*)&Ks[cur ^ 1][sr][sc]      = kr0;
      *(uint4*)&Ks[cur ^ 1][sr][sc + 8]  = kr1;
      *(uint4*)&Vts[cur ^ 1][sr][sc]     = vr0;
      *(uint4*)&Vts[cur ^ 1][sr][sc + 8] = vr1;
      __syncthreads();
#pragma unroll
      for (int nb = 0; nb < 4; ++nb) bcur[nb] = bnx[nb];
    }
  }

  const size_t rowb = (size_t)(z * NH + h) * LQ + i0 + w * 16 + g * 4;
#pragma unroll
  for (int nb = 0; nb < 4; ++nb)
#pragma unroll
    for (int r = 0; r < 4; ++r)
      Opart[(rowb + r) * HD + nb * 16 + c] = acc_o[nb][r];
  if (c == 0) {
#pragma unroll
    for (int r = 0; r < 4; ++r) {
      ml[(rowb + r) * 2]     = m_run[r];
      ml[(rowb + r) * 2 + 1] = l_run[r];
    }
  }
}

// ============ kernel 4: combine the two j-halves ============
__global__ __launch_bounds__(256) void combine_k(
    const float* __restrict__ Opart, const float* __restrict__ ml,
    unsigned short* __restrict__ attno) {
  const int t = threadIdx.x;
  const int row = blockIdx.x * 4 + (t >> 6);
  const int d = t & 63;
  const int h = row >> 10, i = row & 1023;
  const size_t r0 = (size_t)h * LQ + i;
  const size_t r1 = (size_t)(NH + h) * LQ + i;
  const float m0 = ml[r0 * 2], l0 = ml[r0 * 2 + 1];
  const float m1 = ml[r1 * 2], l1 = ml[r1 * 2 + 1];
  const float M = fmaxf(m0, m1);
  const float a0 = __expf(m0 - M), a1 = __expf(m1 - M);
  const float L = a0 * l0 + a1 * l1;
  const float o = (a0 * Opart[r0 * HD + d] + a1 * Opart[r1 * HD + d]) / L;
  attno[(size_t)i * CS + h * HD + d] = f2bf(o);
}

// ============ kernel 5: final GEMM (64x128 tiles) + gated residual ============
__global__ __launch_bounds__(256) void gemm_final_k(
    const unsigned short* __restrict__ A, const unsigned short* __restrict__ wt,
    const float* __restrict__ bout, const float* __restrict__ single,
    const float* __restrict__ gpre, float* __restrict__ out) {
  __shared__ __align__(16) unsigned short As[64][88];
  __shared__ __align__(16) unsigned short Bs[128][88];
  const int t = threadIdx.x;
  const int wave = t >> 6, lane = t & 63, g = lane >> 4, c = lane & 15;
  const int wm = wave >> 1, wn = wave & 1;
  const int m0 = blockIdx.y * 64;
  const int nl0 = blockIdx.x * 128;
  const unsigned short* B = wt + (size_t)4 * CS * CS;

  f32x4 acc[2][4];
#pragma unroll
  for (int i = 0; i < 2; ++i)
#pragma unroll
    for (int j = 0; j < 4; ++j) acc[i][j] = (f32x4){0.f, 0.f, 0.f, 0.f};

  const int sra = t >> 2, sha = (t & 3) * 16;
  const int srb = t >> 1, shb = (t & 1) * 32;
  for (int kt = 0; kt < CS; kt += 64) {
    __syncthreads();
#pragma unroll
    for (int u = 0; u < 2; ++u)
      *(uint4*)&As[sra][sha + u * 8] = *(const uint4*)&A[(size_t)(m0 + sra) * CS + kt + sha + u * 8];
#pragma unroll
    for (int u = 0; u < 4; ++u)
      *(uint4*)&Bs[srb][shb + u * 8] = *(const uint4*)&B[(size_t)(nl0 + srb) * CS + kt + shb + u * 8];
    __syncthreads();
#pragma unroll
    for (int kk = 0; kk < 64; kk += 32) {
      bf16x8 af[2], bfr[4];
#pragma unroll
      for (int i = 0; i < 2; ++i) af[i] = *(const bf16x8*)&As[wm * 32 + i * 16 + c][kk + g * 8];
#pragma unroll
      for (int j = 0; j < 4; ++j) bfr[j] = *(const bf16x8*)&Bs[wn * 64 + j * 16 + c][kk + g * 8];
#pragma unroll
      for (int i = 0; i < 2; ++i)
#pragma unroll
        for (int j = 0; j < 4; ++j)
          acc[i][j] = __builtin_amdgcn_mfma_f32_16x16x32_bf16(af[i], bfr[j], acc[i][j], 0, 0, 0);
    }
  }

#pragma unroll
  for (int i = 0; i < 2; ++i) {
#pragma unroll
    for (int j = 0; j < 4; ++j) {
      const int mb = m0 + wm * 32 + i * 16 + g * 4;
      const int nn = nl0 + wn * 64 + j * 16 + c;
      const float bb = bout[nn];
      const f32x4 a = acc[i][j];
#pragma unroll
      for (int r = 0; r < 4; ++r) {
        const size_t idx = (size_t)(mb + r) * CS + nn;
        const float gate = 1.f / (1.f + __expf(-gpre[idx]));
        out[idx] = single[idx] + gate * (a[r] + bb);
      }
    }
  }
}

extern "C" void kernel_launch(void* const* d_in, const int* in_sizes, int n_in,
                              void* d_out, int out_size, void* d_ws, size_t ws_size,
                              hipStream_t stream) {
  const float* single = (const float*)d_in[0];
  const float* pair   = (const float*)d_in[1];
  const float* ln_s_g = (const float*)d_in[2];
  const float* ln_s_b = (const float*)d_in[3];
  const float* ln_z_g = (const float*)d_in[4];
  const float* ln_z_b = (const float*)d_in[5];
  const float* Wq     = (const float*)d_in[6];
  const float* Wk     = (const float*)d_in[7];
  const float* Wv     = (const float*)d_in[8];
  const float* Wb     = (const float*)d_in[9];
  const float* Wout   = (const float*)d_in[10];
  const float* bout   = (const float*)d_in[11];
  const float* Wgate  = (const float*)d_in[12];
  const float* bgate  = (const float*)d_in[13];
  float* out = (float*)d_out;

  unsigned short* s_bf  = (unsigned short*)d_ws;
  unsigned short* wt    = s_bf  + (size_t)LQ * CS;
  unsigned short* q_bf  = wt    + (size_t)5 * CS * CS;
  unsigned short* k_bf  = q_bf  + (size_t)LQ * CS;
  unsigned short* vt_bf = k_bf  + (size_t)LQ * CS;
  unsigned short* attno = vt_bf + (size_t)CS * LQ;
  unsigned short* biasF = attno + (size_t)LQ * CS;
  float* gpre  = (float*)(biasF + (size_t)NH * LQ * LQ);
  float* Opart = gpre  + (size_t)LQ * CS;
  float* mlw   = Opart + (size_t)2 * NH * LQ * HD;

  hipLaunchKernelGGL(ln_wconv_k, dim3(LQ + 720), dim3(256), 0, stream,
                     single, ln_s_g, ln_s_b, s_bf, Wq, Wk, Wv, Wgate, Wout, wt);
  hipLaunchKernelGGL(qkvg_pair_k, dim3(192 + 1024), dim3(256), 0, stream,
                     s_bf, wt, bgate, q_bf, k_bf, vt_bf, gpre,
                     pair, ln_z_g, ln_z_b, Wb, biasF);
  hipLaunchKernelGGL(attn_k, dim3(16, NH, 2), dim3(256), 0, stream,
                     q_bf, k_bf, vt_bf, biasF, Opart, mlw);
  hipLaunchKernelGGL(combine_k, dim3(3072), dim3(256), 0, stream,
                     Opart, mlw, attno);
  hipLaunchKernelGGL(gemm_final_k, dim3(6, 16), dim3(256), 0, stream,
                     attno, wt, bout, single, gpre, out);
}

// Round 6
// 123.222 us; speedup vs baseline: 3.7652x; 1.0199x over previous
//
#include <hip/hip_runtime.h>

#define LQ 1024
#define CS 768
#define CZ 64
#define NH 12
#define HD 64

typedef float4 f4;
using bf16x8 = __attribute__((ext_vector_type(8))) short;
using f32x4  = __attribute__((ext_vector_type(4))) float;

static __device__ __forceinline__ unsigned short f2bf(float f) {
  unsigned int u = __float_as_uint(f);
  u += 0x7fffu + ((u >> 16) & 1u);
  return (unsigned short)(u >> 16);
}
static __device__ __forceinline__ float bf2f(unsigned short b) {
  return __uint_as_float(((unsigned int)b) << 16);
}

// ============ kernel 1: ln_single + weight convert/transpose (fused) ============
__global__ __launch_bounds__(256) void ln_wconv_k(
    const float* __restrict__ x, const float* __restrict__ g,
    const float* __restrict__ b, unsigned short* __restrict__ s_out,
    const float* __restrict__ Wq, const float* __restrict__ Wk,
    const float* __restrict__ Wv, const float* __restrict__ Wg,
    const float* __restrict__ Wo, unsigned short* __restrict__ wt) {
  const int bid = blockIdx.x;
  const int t = threadIdx.x;
  if (bid < LQ) {
    const int row = bid;
    const float* xr = x + (size_t)row * CS;
    float v0 = xr[t], v1 = xr[t + 256], v2 = xr[t + 512];
    float s1 = v0 + v1 + v2;
    float s2 = v0 * v0 + v1 * v1 + v2 * v2;
#pragma unroll
    for (int m = 1; m < 64; m <<= 1) {
      s1 += __shfl_xor(s1, m);
      s2 += __shfl_xor(s2, m);
    }
    __shared__ float r1[4], r2[4];
    const int wid = t >> 6;
    if ((t & 63) == 0) { r1[wid] = s1; r2[wid] = s2; }
    __syncthreads();
    s1 = r1[0] + r1[1] + r1[2] + r1[3];
    s2 = r2[0] + r2[1] + r2[2] + r2[3];
    const float mu = s1 * (1.f / CS);
    const float var = s2 * (1.f / CS) - mu * mu;
    const float rs = rsqrtf(var + 1e-5f);
    s_out[(size_t)row * CS + t]       = f2bf((v0 - mu) * rs * g[t]       + b[t]);
    s_out[(size_t)row * CS + t + 256] = f2bf((v1 - mu) * rs * g[t + 256] + b[t + 256]);
    s_out[(size_t)row * CS + t + 512] = f2bf((v2 - mu) * rs * g[t + 512] + b[t + 512]);
  } else {
    int r = bid - LQ;                    // 0..719
    const int bz = r / 144; r %= 144;
    const int n0 = (r % 12) * 64, k0 = (r / 12) * 64;
    const float* W;
    switch (bz) {
      case 0: W = Wq; break;
      case 1: W = Wk; break;
      case 2: W = Wv; break;
      case 3: W = Wg; break;
      default: W = Wo; break;
    }
    unsigned short* o = wt + (size_t)bz * CS * CS;
    __shared__ float T[64][68];
    {
      const int rr = t >> 4, c = (t & 15) * 4;
#pragma unroll
      for (int u = 0; u < 4; ++u) {
        const f4 v = *(const f4*)&W[(size_t)(k0 + rr + u * 16) * CS + n0 + c];
        *(f4*)&T[rr + u * 16][c] = v;
      }
    }
    __syncthreads();
    {
      const int rn = t >> 2, ck = (t & 3) * 16;
      __align__(16) unsigned short tmp[16];
#pragma unroll
      for (int u = 0; u < 16; ++u) tmp[u] = f2bf(T[ck + u][rn]);
      unsigned short* dst = &o[(size_t)(n0 + rn) * CS + k0 + ck];
      *(uint4*)dst = ((const uint4*)tmp)[0];
      *(uint4*)(dst + 8) = ((const uint4*)tmp)[1];
    }
  }
}

// ============ kernel 2: QKVG GEMM (384 blocks, 64x128 tiles) || pair-bias MFMA (1024 blocks) ============
// biasF layout (attn-fragment), element (h, i, j):
//   flat = (((h*64 + (i>>4))*16 + (j>>6))*4 + ((j>>4)&3))*256
//          + ((i>>2)&3)*64 + (j&15)*4 + (i&3)
__global__ __launch_bounds__(256) void qkvg_pair_k(
    const unsigned short* __restrict__ s, const unsigned short* __restrict__ wt,
    const float* __restrict__ bg,
    unsigned short* __restrict__ qb, unsigned short* __restrict__ kb,
    unsigned short* __restrict__ vt, float* __restrict__ gpre,
    const float* __restrict__ pair, const float* __restrict__ zg,
    const float* __restrict__ zb, const float* __restrict__ Wb,
    unsigned short* __restrict__ biasF) {
  __shared__ __align__(16) unsigned short sm[64 * 88 + 128 * 88];  // 33.8 KB, GEMM path only
  const int bid = blockIdx.x;
  const int t = threadIdx.x;
  const int w = t >> 6, lane = t & 63, g = lane >> 4, c = lane & 15;

  if (bid < 384) {
    // ---- QKVG GEMM path: 64x128 tile, BK=64, 2x4 acc (keeps VGPR low) ----
    unsigned short (*As)[88] = (unsigned short (*)[88])sm;
    unsigned short (*Bs)[88] = (unsigned short (*)[88])(sm + 64 * 88);
    const int wm = w >> 1, wn = w & 1;
    const int bx = bid % 24, by = bid / 24;
    const int m0 = by * 64;
    const int wid = bx / 6;
    const int nl0 = (bx % 6) * 128;
    const unsigned short* B = wt + (size_t)wid * CS * CS;

    f32x4 acc[2][4];
#pragma unroll
    for (int i = 0; i < 2; ++i)
#pragma unroll
      for (int j = 0; j < 4; ++j) acc[i][j] = (f32x4){0.f, 0.f, 0.f, 0.f};

    const int sra = t >> 2, sha = (t & 3) * 16;
    const int srb = t >> 1, shb = (t & 1) * 32;
    for (int kt = 0; kt < CS; kt += 64) {
      __syncthreads();
#pragma unroll
      for (int u = 0; u < 2; ++u)
        *(uint4*)&As[sra][sha + u * 8] = *(const uint4*)&s[(size_t)(m0 + sra) * CS + kt + sha + u * 8];
#pragma unroll
      for (int u = 0; u < 4; ++u)
        *(uint4*)&Bs[srb][shb + u * 8] = *(const uint4*)&B[(size_t)(nl0 + srb) * CS + kt + shb + u * 8];
      __syncthreads();
#pragma unroll
      for (int kk = 0; kk < 64; kk += 32) {
        bf16x8 af[2], bfr[4];
#pragma unroll
        for (int i = 0; i < 2; ++i) af[i] = *(const bf16x8*)&As[wm * 32 + i * 16 + c][kk + g * 8];
#pragma unroll
        for (int j = 0; j < 4; ++j) bfr[j] = *(const bf16x8*)&Bs[wn * 64 + j * 16 + c][kk + g * 8];
#pragma unroll
        for (int i = 0; i < 2; ++i)
#pragma unroll
          for (int j = 0; j < 4; ++j)
            acc[i][j] = __builtin_amdgcn_mfma_f32_16x16x32_bf16(af[i], bfr[j], acc[i][j], 0, 0, 0);
      }
    }
#pragma unroll
    for (int i = 0; i < 2; ++i) {
#pragma unroll
      for (int j = 0; j < 4; ++j) {
        const int mb = m0 + wm * 32 + i * 16 + g * 4;
        const int nn = nl0 + wn * 64 + j * 16 + c;
        const f32x4 a = acc[i][j];
        if (wid == 0) {
#pragma unroll
          for (int r = 0; r < 4; ++r) qb[(size_t)(mb + r) * CS + nn] = f2bf(a[r] * 0.125f);
        } else if (wid == 1) {
#pragma unroll
          for (int r = 0; r < 4; ++r) kb[(size_t)(mb + r) * CS + nn] = f2bf(a[r]);
        } else if (wid == 2) {
          ushort4 pk;
          pk.x = f2bf(a[0]); pk.y = f2bf(a[1]); pk.z = f2bf(a[2]); pk.w = f2bf(a[3]);
          *(ushort4*)&vt[(size_t)nn * LQ + mb] = pk;
        } else {
          const float bb = bg[nn];
#pragma unroll
          for (int r = 0; r < 4; ++r) gpre[(size_t)(mb + r) * CS + nn] = a[r] + bb;
        }
      }
    }
  } else {
    // ---- pair-bias path: LDS-free register-fragment MFMA, 2-deep load pipeline ----
    const int pid = bid - 384;
    const int i0 = (pid >> 2) * 4;
    const int j0 = (pid & 3) * 256;

    // hoisted LN gamma/beta registers for this lane's channels (g*8.. / 32+g*8..)
    float zgr[16], zbr[16];
    *(f4*)&zgr[0]  = *(const f4*)&zg[g * 8];
    *(f4*)&zgr[4]  = *(const f4*)&zg[g * 8 + 4];
    *(f4*)&zgr[8]  = *(const f4*)&zg[32 + g * 8];
    *(f4*)&zgr[12] = *(const f4*)&zg[32 + g * 8 + 4];
    *(f4*)&zbr[0]  = *(const f4*)&zb[g * 8];
    *(f4*)&zbr[4]  = *(const f4*)&zb[g * 8 + 4];
    *(f4*)&zbr[8]  = *(const f4*)&zb[32 + g * 8];
    *(f4*)&zbr[12] = *(const f4*)&zb[32 + g * 8 + 4];

    // hoisted Wb B-fragment: col = head c, k = channel
    bf16x8 wf0, wf1;
    const int csafe = (c < NH) ? c : 0;
#pragma unroll
    for (int u = 0; u < 8; ++u) {
      const float w0 = (c < NH) ? Wb[(g * 8 + u) * NH + csafe] : 0.f;
      const float w1 = (c < NH) ? Wb[(32 + g * 8 + u) * NH + csafe] : 0.f;
      wf0[u] = (short)f2bf(w0);
      wf1[u] = (short)f2bf(w1);
    }

    const int il = c & 3, jl = c >> 2;   // lane's pair: row i0+il, col jw+jl
    const int irow = i0 + il;
    const int gi = i0 >> 4, ga = (i0 >> 2) & 3;
    const size_t hd_base = ((size_t)gi * 16) * 4 * 256 + (size_t)ga * 64;

    auto ldx = [&](int it, float* x0, float* x1) {
      const int jw = j0 + w * 64 + it * 4;
      const float* src = pair + ((size_t)irow * LQ + (jw + jl)) * CZ;
      *(f4*)&x0[0] = *(const f4*)&src[g * 8];
      *(f4*)&x0[4] = *(const f4*)&src[g * 8 + 4];
      *(f4*)&x1[0] = *(const f4*)&src[32 + g * 8];
      *(f4*)&x1[4] = *(const f4*)&src[32 + g * 8 + 4];
    };
    auto proc = [&](int it, const float* x0, const float* x1) {
      float s1 = (((x0[0] + x0[1]) + (x0[2] + x0[3])) + ((x0[4] + x0[5]) + (x0[6] + x0[7])))
               + (((x1[0] + x1[1]) + (x1[2] + x1[3])) + ((x1[4] + x1[5]) + (x1[6] + x1[7])));
      float s2 = (((x0[0]*x0[0] + x0[1]*x0[1]) + (x0[2]*x0[2] + x0[3]*x0[3]))
               +  ((x0[4]*x0[4] + x0[5]*x0[5]) + (x0[6]*x0[6] + x0[7]*x0[7])))
               + (((x1[0]*x1[0] + x1[1]*x1[1]) + (x1[2]*x1[2] + x1[3]*x1[3]))
               +  ((x1[4]*x1[4] + x1[5]*x1[5]) + (x1[6]*x1[6] + x1[7]*x1[7])));
      s1 += __shfl_xor(s1, 16); s1 += __shfl_xor(s1, 32);
      s2 += __shfl_xor(s2, 16); s2 += __shfl_xor(s2, 32);
      const float mu = s1 * (1.f / CZ);
      const float var = s2 * (1.f / CZ) - mu * mu;
      const float rs = rsqrtf(var + 1e-5f);

      bf16x8 a0, a1;
#pragma unroll
      for (int u = 0; u < 8; ++u) {
        a0[u] = (short)f2bf((x0[u] - mu) * rs * zgr[u] + zbr[u]);
        a1[u] = (short)f2bf((x1[u] - mu) * rs * zgr[8 + u] + zbr[8 + u]);
      }

      f32x4 dd = (f32x4){0.f, 0.f, 0.f, 0.f};
      dd = __builtin_amdgcn_mfma_f32_16x16x32_bf16(a0, wf0, dd, 0, 0, 0);
      dd = __builtin_amdgcn_mfma_f32_16x16x32_bf16(a1, wf1, dd, 0, 0, 0);

      // D: lane (g,c) holds pairs (i0+r, jw+g), head c -> one ushort4 store
      if (c < NH) {
        const int jj = j0 + w * 64 + it * 4 + g;
        const size_t base = ((size_t)c * 64) * 16384
                          + hd_base
                          + (size_t)(jj >> 6) * 1024
                          + (size_t)((jj >> 4) & 3) * 256
                          + (jj & 15) * 4;
        ushort4 st;
        st.x = f2bf(dd[0]); st.y = f2bf(dd[1]); st.z = f2bf(dd[2]); st.w = f2bf(dd[3]);
        *(ushort4*)&biasF[base] = st;
      }
    };

    float xa0[8], xa1[8], xb0[8], xb1[8];
    ldx(0, xa0, xa1);
    for (int ip = 0; ip < 8; ++ip) {
      ldx(2 * ip + 1, xb0, xb1);
      proc(2 * ip, xa0, xa1);
      if (ip < 7) ldx(2 * ip + 2, xa0, xa1);
      proc(2 * ip + 1, xb0, xb1);
    }
  }
}

// ============ kernel 3: MFMA flash attention, j-split x2, double-buffered ============
__global__ __launch_bounds__(256) void attn_k(
    const unsigned short* __restrict__ q, const unsigned short* __restrict__ k,
    const unsigned short* __restrict__ vt, const unsigned short* __restrict__ biasF,
    float* __restrict__ Opart, float* __restrict__ ml) {
  __shared__ __align__(16) unsigned short Qs[64][88];
  __shared__ __align__(16) unsigned short Ks[2][64][88];
  __shared__ __align__(16) unsigned short Vts[2][64][88];
  __shared__ __align__(16) unsigned short Ps[4][16][88];
  const int bx = blockIdx.x, h = blockIdx.y, z = blockIdx.z;
  const int i0 = bx * 64;
  const int jb = z * 512;
  const int t = threadIdx.x;
  const int w = t >> 6, lane = t & 63, g = lane >> 4, c = lane & 15;
  const int sr = t >> 2, sc = (t & 3) * 16;

#pragma unroll
  for (int u = 0; u < 2; ++u) {
    *(uint4*)&Qs[sr][sc + u * 8]     = *(const uint4*)&q[(size_t)(i0 + sr) * CS + h * HD + sc + u * 8];
    *(uint4*)&Ks[0][sr][sc + u * 8]  = *(const uint4*)&k[(size_t)(jb + sr) * CS + h * HD + sc + u * 8];
    *(uint4*)&Vts[0][sr][sc + u * 8] = *(const uint4*)&vt[(size_t)(h * HD + sr) * LQ + jb + sc + u * 8];
  }
  const size_t bbase = ((((size_t)h * 64 + (bx * 4 + w)) * 16 + (size_t)z * 8) * 4) * 256 + lane * 4;
  ushort4 bcur[4];
#pragma unroll
  for (int nb = 0; nb < 4; ++nb) bcur[nb] = *(const ushort4*)&biasF[bbase + nb * 256];
  __syncthreads();

  const bf16x8 aq0 = *(const bf16x8*)&Qs[w * 16 + c][g * 8];
  const bf16x8 aq1 = *(const bf16x8*)&Qs[w * 16 + c][32 + g * 8];

  f32x4 acc_o[4];
#pragma unroll
  for (int nb = 0; nb < 4; ++nb) acc_o[nb] = (f32x4){0.f, 0.f, 0.f, 0.f};
  float m_run[4] = {-1e30f, -1e30f, -1e30f, -1e30f};
  float l_run[4] = {0.f, 0.f, 0.f, 0.f};

  for (int jt = 0; jt < 8; ++jt) {
    const int cur = jt & 1;
    uint4 kr0, kr1, vr0, vr1;
    ushort4 bnx[4];
    if (jt < 7) {
      const int jn = jb + (jt + 1) * 64;
      kr0 = *(const uint4*)&k[(size_t)(jn + sr) * CS + h * HD + sc];
      kr1 = *(const uint4*)&k[(size_t)(jn + sr) * CS + h * HD + sc + 8];
      vr0 = *(const uint4*)&vt[(size_t)(h * HD + sr) * LQ + jn + sc];
      vr1 = *(const uint4*)&vt[(size_t)(h * HD + sr) * LQ + jn + sc + 8];
#pragma unroll
      for (int nb = 0; nb < 4; ++nb)
        bnx[nb] = *(const ushort4*)&biasF[bbase + (size_t)(jt + 1) * 1024 + nb * 256];
    }

    f32x4 sa[4];
#pragma unroll
    for (int nb = 0; nb < 4; ++nb) {
      f32x4 ci;
      ci[0] = bf2f(bcur[nb].x); ci[1] = bf2f(bcur[nb].y);
      ci[2] = bf2f(bcur[nb].z); ci[3] = bf2f(bcur[nb].w);
      const bf16x8 b0 = *(const bf16x8*)&Ks[cur][nb * 16 + c][g * 8];
      const bf16x8 b1 = *(const bf16x8*)&Ks[cur][nb * 16 + c][32 + g * 8];
      ci = __builtin_amdgcn_mfma_f32_16x16x32_bf16(aq0, b0, ci, 0, 0, 0);
      ci = __builtin_amdgcn_mfma_f32_16x16x32_bf16(aq1, b1, ci, 0, 0, 0);
      sa[nb] = ci;
    }

    float mt[4];
#pragma unroll
    for (int r = 0; r < 4; ++r) {
      float v = fmaxf(fmaxf(sa[0][r], sa[1][r]), fmaxf(sa[2][r], sa[3][r]));
      v = fmaxf(v, __shfl_xor(v, 1));
      v = fmaxf(v, __shfl_xor(v, 2));
      v = fmaxf(v, __shfl_xor(v, 4));
      v = fmaxf(v, __shfl_xor(v, 8));
      mt[r] = v;
    }
    float scale[4], ps[4];
#pragma unroll
    for (int r = 0; r < 4; ++r) {
      const float mn = fmaxf(m_run[r], mt[r]);
      scale[r] = __expf(m_run[r] - mn);
      m_run[r] = mn;
      ps[r] = 0.f;
    }
#pragma unroll
    for (int nb = 0; nb < 4; ++nb) {
#pragma unroll
      for (int r = 0; r < 4; ++r) {
        const float p = __expf(sa[nb][r] - m_run[r]);
        ps[r] += p;
        Ps[w][g * 4 + r][nb * 16 + c] = f2bf(p);
      }
    }
#pragma unroll
    for (int r = 0; r < 4; ++r) {
      float v = ps[r];
      v += __shfl_xor(v, 1);
      v += __shfl_xor(v, 2);
      v += __shfl_xor(v, 4);
      v += __shfl_xor(v, 8);
      l_run[r] = l_run[r] * scale[r] + v;
#pragma unroll
      for (int nb = 0; nb < 4; ++nb) acc_o[nb][r] *= scale[r];
    }

#pragma unroll
    for (int kb = 0; kb < 2; ++kb) {
      const bf16x8 pa = *(const bf16x8*)&Ps[w][c][kb * 32 + g * 8];
#pragma unroll
      for (int nb = 0; nb < 4; ++nb) {
        const bf16x8 bv = *(const bf16x8*)&Vts[cur][nb * 16 + c][kb * 32 + g * 8];
        acc_o[nb] = __builtin_amdgcn_mfma_f32_16x16x32_bf16(pa, bv, acc_o[nb], 0, 0, 0);
      }
    }

    if (jt < 7) {
      *(uint4*)&Ks[cur ^ 1][sr][sc]      = kr0;
      *(uint4*)&Ks[cur ^ 1][sr][sc + 8]  = kr1;
      *(uint4*)&Vts[cur ^ 1][sr][sc]     = vr0;
      *(uint4*)&Vts[cur ^ 1][sr][sc + 8] = vr1;
      __syncthreads();
#pragma unroll
      for (int nb = 0; nb < 4; ++nb) bcur[nb] = bnx[nb];
    }
  }

  const size_t rowb = (size_t)(z * NH + h) * LQ + i0 + w * 16 + g * 4;
#pragma unroll
  for (int nb = 0; nb < 4; ++nb)
#pragma unroll
    for (int r = 0; r < 4; ++r)
      Opart[(rowb + r) * HD + nb * 16 + c] = acc_o[nb][r];
  if (c == 0) {
#pragma unroll
    for (int r = 0; r < 4; ++r) {
      ml[(rowb + r) * 2]     = m_run[r];
      ml[(rowb + r) * 2 + 1] = l_run[r];
    }
  }
}

// ============ kernel 4: combine the two j-halves ============
__global__ __launch_bounds__(256) void combine_k(
    const float* __restrict__ Opart, const float* __restrict__ ml,
    unsigned short* __restrict__ attno) {
  const int t = threadIdx.x;
  const int row = blockIdx.x * 4 + (t >> 6);
  const int d = t & 63;
  const int h = row >> 10, i = row & 1023;
  const size_t r0 = (size_t)h * LQ + i;
  const size_t r1 = (size_t)(NH + h) * LQ + i;
  const float m0 = ml[r0 * 2], l0 = ml[r0 * 2 + 1];
  const float m1 = ml[r1 * 2], l1 = ml[r1 * 2 + 1];
  const float M = fmaxf(m0, m1);
  const float a0 = __expf(m0 - M), a1 = __expf(m1 - M);
  const float L = a0 * l0 + a1 * l1;
  const float o = (a0 * Opart[r0 * HD + d] + a1 * Opart[r1 * HD + d]) / L;
  attno[(size_t)i * CS + h * HD + d] = f2bf(o);
}

// ============ kernel 5: final GEMM (64x128 tiles) + gated residual ============
__global__ __launch_bounds__(256) void gemm_final_k(
    const unsigned short* __restrict__ A, const unsigned short* __restrict__ wt,
    const float* __restrict__ bout, const float* __restrict__ single,
    const float* __restrict__ gpre, float* __restrict__ out) {
  __shared__ __align__(16) unsigned short As[64][88];
  __shared__ __align__(16) unsigned short Bs[128][88];
  const int t = threadIdx.x;
  const int wave = t >> 6, lane = t & 63, g = lane >> 4, c = lane & 15;
  const int wm = wave >> 1, wn = wave & 1;
  const int m0 = blockIdx.y * 64;
  const int nl0 = blockIdx.x * 128;
  const unsigned short* B = wt + (size_t)4 * CS * CS;

  f32x4 acc[2][4];
#pragma unroll
  for (int i = 0; i < 2; ++i)
#pragma unroll
    for (int j = 0; j < 4; ++j) acc[i][j] = (f32x4){0.f, 0.f, 0.f, 0.f};

  const int sra = t >> 2, sha = (t & 3) * 16;
  const int srb = t >> 1, shb = (t & 1) * 32;
  for (int kt = 0; kt < CS; kt += 64) {
    __syncthreads();
#pragma unroll
    for (int u = 0; u < 2; ++u)
      *(uint4*)&As[sra][sha + u * 8] = *(const uint4*)&A[(size_t)(m0 + sra) * CS + kt + sha + u * 8];
#pragma unroll
    for (int u = 0; u < 4; ++u)
      *(uint4*)&Bs[srb][shb + u * 8] = *(const uint4*)&B[(size_t)(nl0 + srb) * CS + kt + shb + u * 8];
    __syncthreads();
#pragma unroll
    for (int kk = 0; kk < 64; kk += 32) {
      bf16x8 af[2], bfr[4];
#pragma unroll
      for (int i = 0; i < 2; ++i) af[i] = *(const bf16x8*)&As[wm * 32 + i * 16 + c][kk + g * 8];
#pragma unroll
      for (int j = 0; j < 4; ++j) bfr[j] = *(const bf16x8*)&Bs[wn * 64 + j * 16 + c][kk + g * 8];
#pragma unroll
      for (int i = 0; i < 2; ++i)
#pragma unroll
        for (int j = 0; j < 4; ++j)
          acc[i][j] = __builtin_amdgcn_mfma_f32_16x16x32_bf16(af[i], bfr[j], acc[i][j], 0, 0, 0);
    }
  }

#pragma unroll
  for (int i = 0; i < 2; ++i) {
#pragma unroll
    for (int j = 0; j < 4; ++j) {
      const int mb = m0 + wm * 32 + i * 16 + g * 4;
      const int nn = nl0 + wn * 64 + j * 16 + c;
      const float bb = bout[nn];
      const f32x4 a = acc[i][j];
#pragma unroll
      for (int r = 0; r < 4; ++r) {
        const size_t idx = (size_t)(mb + r) * CS + nn;
        const float gate = 1.f / (1.f + __expf(-gpre[idx]));
        out[idx] = single[idx] + gate * (a[r] + bb);
      }
    }
  }
}

extern "C" void kernel_launch(void* const* d_in, const int* in_sizes, int n_in,
                              void* d_out, int out_size, void* d_ws, size_t ws_size,
                              hipStream_t stream) {
  const float* single = (const float*)d_in[0];
  const float* pair   = (const float*)d_in[1];
  const float* ln_s_g = (const float*)d_in[2];
  const float* ln_s_b = (const float*)d_in[3];
  const float* ln_z_g = (const float*)d_in[4];
  const float* ln_z_b = (const float*)d_in[5];
  const float* Wq     = (const float*)d_in[6];
  const float* Wk     = (const float*)d_in[7];
  const float* Wv     = (const float*)d_in[8];
  const float* Wb     = (const float*)d_in[9];
  const float* Wout   = (const float*)d_in[10];
  const float* bout   = (const float*)d_in[11];
  const float* Wgate  = (const float*)d_in[12];
  const float* bgate  = (const float*)d_in[13];
  float* out = (float*)d_out;

  unsigned short* s_bf  = (unsigned short*)d_ws;
  unsigned short* wt    = s_bf  + (size_t)LQ * CS;
  unsigned short* q_bf  = wt    + (size_t)5 * CS * CS;
  unsigned short* k_bf  = q_bf  + (size_t)LQ * CS;
  unsigned short* vt_bf = k_bf  + (size_t)LQ * CS;
  unsigned short* attno = vt_bf + (size_t)CS * LQ;
  unsigned short* biasF = attno + (size_t)LQ * CS;
  float* gpre  = (float*)(biasF + (size_t)NH * LQ * LQ);
  float* Opart = gpre  + (size_t)LQ * CS;
  float* mlw   = Opart + (size_t)2 * NH * LQ * HD;

  hipLaunchKernelGGL(ln_wconv_k, dim3(LQ + 720), dim3(256), 0, stream,
                     single, ln_s_g, ln_s_b, s_bf, Wq, Wk, Wv, Wgate, Wout, wt);
  hipLaunchKernelGGL(qkvg_pair_k, dim3(384 + 1024), dim3(256), 0, stream,
                     s_bf, wt, bgate, q_bf, k_bf, vt_bf, gpre,
                     pair, ln_z_g, ln_z_b, Wb, biasF);
  hipLaunchKernelGGL(attn_k, dim3(16, NH, 2), dim3(256), 0, stream,
                     q_bf, k_bf, vt_bf, biasF, Opart, mlw);
  hipLaunchKernelGGL(combine_k, dim3(3072), dim3(256), 0, stream,
                     Opart, mlw, attno);
  hipLaunchKernelGGL(gemm_final_k, dim3(6, 16), dim3(256), 0, stream,
                     attno, wt, bout, single, gpre, out);
}